// Round 1
// baseline (1868.327 us; speedup 1.0000x reference)
//
#include <hip/hip_runtime.h>
#include <math.h>

#define N_NODES 50000
#define D 128
#define LAYERS 3
#define DZ (3 * 128)
#define DOUT 40

// ---------------- CSR build ----------------

__global__ void count_deg_kernel(const int* __restrict__ dst, int E, int* __restrict__ deg) {
    int e = blockIdx.x * blockDim.x + threadIdx.x;
    if (e < E) atomicAdd(&deg[dst[e]], 1);
}

// single-block exclusive scan over n (<= 1024*chunk) ints
__global__ void scan_kernel(const int* __restrict__ deg, int n, int* __restrict__ offs) {
    __shared__ int s[1024];
    int t = threadIdx.x;
    int chunk = (n + 1023) / 1024;
    int base = t * chunk;
    int sum = 0;
    for (int i = 0; i < chunk; ++i) {
        int idx = base + i;
        if (idx < n) sum += deg[idx];
    }
    s[t] = sum;
    __syncthreads();
    for (int off = 1; off < 1024; off <<= 1) {
        int v = (t >= off) ? s[t - off] : 0;
        __syncthreads();
        s[t] += v;
        __syncthreads();
    }
    int run = s[t] - sum;  // exclusive prefix of this thread's chunk
    for (int i = 0; i < chunk; ++i) {
        int idx = base + i;
        if (idx < n) { offs[idx] = run; run += deg[idx]; }
    }
    if (t == 1023) offs[n] = s[1023];
}

__global__ void fill_adj_kernel(const int* __restrict__ src, const int* __restrict__ dst, int E,
                                const int* __restrict__ offs, int* __restrict__ cursor,
                                int* __restrict__ adj) {
    int e = blockIdx.x * blockDim.x + threadIdx.x;
    if (e < E) {
        int d = dst[e];
        int p = atomicAdd(&cursor[d], 1);
        adj[offs[d] + p] = src[e];
    }
}

// ---------------- mean aggregation ----------------
// block = 256 threads = 2 nodes x 128 feature lanes
__global__ void aggregate_kernel(const float* __restrict__ h, int ldh,
                                 const int* __restrict__ offs, const int* __restrict__ adj,
                                 float* __restrict__ m) {
    int node = blockIdx.x * 2 + (threadIdx.x >> 7);
    int f = threadIdx.x & 127;
    if (node >= N_NODES) return;
    int s = offs[node], e = offs[node + 1];
    float acc = 0.f;
    for (int k = s; k < e; ++k) {
        int sn = adj[k];
        acc += h[sn * ldh + f];
    }
    float deg = (float)(e - s);
    m[node * D + f] = acc * (1.0f / fmaxf(deg, 1.0f));
}

// ---------------- SAGE layer GEMM: out = m@Wl + bl + h@Wr ----------------
// 32 nodes per block, 256 threads; thread (c = tid&127 out-col, half = tid>>7)
#define TN 32
__global__ void sage_gemm_kernel(const float* __restrict__ m,
                                 const float* __restrict__ h, int ldh,
                                 const float* __restrict__ Wl, const float* __restrict__ Wr,
                                 const float* __restrict__ bl,
                                 float* __restrict__ out, int ldo) {
    __shared__ float Wls[16][128];
    __shared__ float Wrs[16][128];
    __shared__ float ms[TN][16];
    __shared__ float hs[TN][16];
    int tid = threadIdx.x;
    int c = tid & 127;
    int half = tid >> 7;
    int n0 = blockIdx.x * TN;
    float acc[16];
#pragma unroll
    for (int j = 0; j < 16; ++j) acc[j] = 0.f;

    for (int k0 = 0; k0 < 128; k0 += 16) {
        for (int i = tid; i < 16 * 128; i += 256) {
            int r = i >> 7, cc = i & 127;
            Wls[r][cc] = Wl[(k0 + r) * 128 + cc];
            Wrs[r][cc] = Wr[(k0 + r) * 128 + cc];
        }
        for (int i = tid; i < TN * 16; i += 256) {
            int r = i >> 4, kk = i & 15;
            int node = n0 + r;
            ms[r][kk] = (node < N_NODES) ? m[node * D + k0 + kk] : 0.f;
            hs[r][kk] = (node < N_NODES) ? h[node * ldh + k0 + kk] : 0.f;
        }
        __syncthreads();
#pragma unroll
        for (int kk = 0; kk < 16; ++kk) {
            float wl = Wls[kk][c];
            float wr = Wrs[kk][c];
#pragma unroll
            for (int j = 0; j < 16; ++j) {
                int r = half * 16 + j;
                acc[j] += ms[r][kk] * wl + hs[r][kk] * wr;
            }
        }
        __syncthreads();
    }
    float b = bl[c];
#pragma unroll
    for (int j = 0; j < 16; ++j) {
        int node = n0 + half * 16 + j;
        if (node < N_NODES) out[node * ldo + c] = acc[j] + b;
    }
}

// ---------------- generic GEMM (Nout=128): out = [relu](A@W + bias) ----------------
__global__ void gemm128_kernel(const float* __restrict__ A, int lda,
                               const float* __restrict__ W,   // [K,128]
                               const float* __restrict__ bias,
                               float* __restrict__ out, int ldo,
                               int K, int relu) {
    __shared__ float Ws[16][128];
    __shared__ float As[TN][16];
    int tid = threadIdx.x;
    int c = tid & 127;
    int half = tid >> 7;
    int n0 = blockIdx.x * TN;
    float acc[16];
#pragma unroll
    for (int j = 0; j < 16; ++j) acc[j] = 0.f;

    for (int k0 = 0; k0 < K; k0 += 16) {
        for (int i = tid; i < 16 * 128; i += 256) {
            int r = i >> 7, cc = i & 127;
            Ws[r][cc] = W[(k0 + r) * 128 + cc];
        }
        for (int i = tid; i < TN * 16; i += 256) {
            int r = i >> 4, kk = i & 15;
            int node = n0 + r;
            As[r][kk] = (node < N_NODES) ? A[node * lda + k0 + kk] : 0.f;
        }
        __syncthreads();
#pragma unroll
        for (int kk = 0; kk < 16; ++kk) {
            float w = Ws[kk][c];
#pragma unroll
            for (int j = 0; j < 16; ++j) {
                acc[j] += As[half * 16 + j][kk] * w;
            }
        }
        __syncthreads();
    }
    float b = bias[c];
#pragma unroll
    for (int j = 0; j < 16; ++j) {
        int node = n0 + half * 16 + j;
        if (node < N_NODES) {
            float v = acc[j] + b;
            if (relu) v = fmaxf(v, 0.f);
            out[node * ldo + c] = v;
        }
    }
}

// ---------------- final layer + log_softmax ----------------
// one block (128 threads) per node
__global__ void mlp2_lsm_kernel(const float* __restrict__ z1,   // [N,128]
                                const float* __restrict__ W2,   // [128,40]
                                const float* __restrict__ b2,
                                float* __restrict__ out) {
    __shared__ float row[128];
    __shared__ float logits[DOUT];
    int n = blockIdx.x;
    int t = threadIdx.x;
    row[t] = z1[n * D + t];
    __syncthreads();
    if (t < DOUT) {
        float acc = b2[t];
#pragma unroll 8
        for (int k = 0; k < 128; ++k) acc += row[k] * W2[k * DOUT + t];
        logits[t] = acc;
    }
    __syncthreads();
    if (t < 64) {
        float v = (t < DOUT) ? logits[t] : -1e30f;
        for (int off = 32; off; off >>= 1) v = fmaxf(v, __shfl_down(v, off));
        float mx = __shfl(v, 0);
        float e = (t < DOUT) ? expf(logits[t] - mx) : 0.f;
        float sum = e;
        for (int off = 32; off; off >>= 1) sum += __shfl_down(sum, off);
        float ls = logf(__shfl(sum, 0));
        if (t < DOUT) out[n * DOUT + t] = logits[t] - mx - ls;
    }
}

// ---------------- launch ----------------

extern "C" void kernel_launch(void* const* d_in, const int* in_sizes, int n_in,
                              void* d_out, int out_size, void* d_ws, size_t ws_size,
                              hipStream_t stream) {
    const float* x   = (const float*)d_in[0];
    const int*   ei  = (const int*)d_in[1];
    const float* Wl  = (const float*)d_in[2];
    const float* Wr  = (const float*)d_in[3];
    const float* bl  = (const float*)d_in[4];
    const float* W1  = (const float*)d_in[5];
    const float* b1  = (const float*)d_in[6];
    const float* W2  = (const float*)d_in[7];
    const float* b2  = (const float*)d_in[8];
    float* out = (float*)d_out;

    const int E = in_sizes[1] / 2;
    const int* src = ei;
    const int* dst = ei + E;

    // workspace carve-up
    char* p = (char*)d_ws;
    int* deg = (int*)p;     p += ((N_NODES + 63) & ~63) * sizeof(int);
    int* offs = (int*)p;    p += ((N_NODES + 1 + 63) & ~63) * sizeof(int);
    int* cursor = (int*)p;  p += ((N_NODES + 63) & ~63) * sizeof(int);
    int* adj = (int*)p;     p += ((E + 63) & ~63) * sizeof(int);
    float* m = (float*)p;   p += (size_t)N_NODES * D * sizeof(float);
    float* z = (float*)p;   p += (size_t)N_NODES * DZ * sizeof(float);
    float* z1 = m;  // m is dead after the last sage_gemm

    hipMemsetAsync(deg, 0, N_NODES * sizeof(int), stream);
    hipMemsetAsync(cursor, 0, N_NODES * sizeof(int), stream);

    int egrid = (E + 255) / 256;
    count_deg_kernel<<<egrid, 256, 0, stream>>>(dst, E, deg);
    scan_kernel<<<1, 1024, 0, stream>>>(deg, N_NODES, offs);
    fill_adj_kernel<<<egrid, 256, 0, stream>>>(src, dst, E, offs, cursor, adj);

    int ngrid2 = (N_NODES + 1) / 2;
    int ggrid = (N_NODES + TN - 1) / TN;

    for (int i = 0; i < LAYERS; ++i) {
        const float* hin = (i == 0) ? x : (z + (size_t)(i - 1) * D);
        int ldh = (i == 0) ? D : DZ;
        aggregate_kernel<<<ngrid2, 256, 0, stream>>>(hin, ldh, offs, adj, m);
        sage_gemm_kernel<<<ggrid, 256, 0, stream>>>(
            m, hin, ldh, Wl + (size_t)i * D * D, Wr + (size_t)i * D * D, bl + (size_t)i * D,
            z + (size_t)i * D, DZ);
    }

    gemm128_kernel<<<ggrid, 256, 0, stream>>>(z, DZ, W1, b1, z1, D, DZ, 1);
    mlp2_lsm_kernel<<<N_NODES, 128, 0, stream>>>(z1, W2, b2, out);
}

// Round 2
// 539.212 us; speedup vs baseline: 3.4649x; 3.4649x over previous
//
#include <hip/hip_runtime.h>
#include <math.h>

#define N_NODES 50000
#define D 128
#define LAYERS 3
#define DZ 384
#define DOUT 40

typedef __attribute__((ext_vector_type(4))) float f32x4;
typedef __attribute__((ext_vector_type(8))) short short8;

static __device__ __forceinline__ unsigned short f2bf(float f) {
    unsigned int u = __float_as_uint(f);
    u += 0x7FFFu + ((u >> 16) & 1u);
    return (unsigned short)(u >> 16);
}
static __device__ __forceinline__ float bf2f(unsigned short s) {
    return __uint_as_float(((unsigned int)s) << 16);
}

// ---------------- CSR build ----------------

__global__ void count_deg_kernel(const int* __restrict__ dst, int E, int* __restrict__ deg) {
    int e = blockIdx.x * blockDim.x + threadIdx.x;
    if (e < E) atomicAdd(&deg[dst[e]], 1);
}

__global__ void scan_kernel(const int* __restrict__ deg, int n, int* __restrict__ offs) {
    __shared__ int s[1024];
    int t = threadIdx.x;
    int chunk = (n + 1023) / 1024;
    int base = t * chunk;
    int sum = 0;
    for (int i = 0; i < chunk; ++i) {
        int idx = base + i;
        if (idx < n) sum += deg[idx];
    }
    s[t] = sum;
    __syncthreads();
    for (int off = 1; off < 1024; off <<= 1) {
        int v = (t >= off) ? s[t - off] : 0;
        __syncthreads();
        s[t] += v;
        __syncthreads();
    }
    int run = s[t] - sum;
    for (int i = 0; i < chunk; ++i) {
        int idx = base + i;
        if (idx < n) { offs[idx] = run; run += deg[idx]; }
    }
    if (t == 1023) offs[n] = s[1023];
}

__global__ void fill_adj_kernel(const int* __restrict__ src, const int* __restrict__ dst, int E,
                                const int* __restrict__ offs, int* __restrict__ cursor,
                                int* __restrict__ adj) {
    int e = blockIdx.x * blockDim.x + threadIdx.x;
    if (e < E) {
        int d = dst[e];
        int p = atomicAdd(&cursor[d], 1);
        adj[offs[d] + p] = src[e];
    }
}

// ---------------- conversions ----------------

// n4 = number of float4 groups
__global__ void cvt_bf16_kernel(const float* __restrict__ in, unsigned short* __restrict__ out, int n4) {
    int i = blockIdx.x * blockDim.x + threadIdx.x;
    if (i >= n4) return;
    const float4 v = ((const float4*)in)[i];
    unsigned int lo = ((unsigned int)f2bf(v.y) << 16) | f2bf(v.x);
    unsigned int hi = ((unsigned int)f2bf(v.w) << 16) | f2bf(v.z);
    ((unsigned int*)out)[i * 2] = lo;
    ((unsigned int*)out)[i * 2 + 1] = hi;
}

// WT[layer][c][k] (k contiguous, 256 wide): k<128 -> Wl[layer][k][c], else Wr[layer][k-128][c]
__global__ void packWT_kernel(const float* __restrict__ Wl, const float* __restrict__ Wr,
                              unsigned short* __restrict__ WT) {
    int i = blockIdx.x * blockDim.x + threadIdx.x;
    if (i >= LAYERS * 128 * 256) return;
    int layer = i >> 15;          // /32768
    int r = i & 32767;
    int c = r >> 8, k = r & 255;
    const float* W = (k < 128) ? (Wl + layer * 16384) : (Wr + layer * 16384);
    WT[i] = f2bf(W[(k & 127) * 128 + c]);
}

// W1T[c][k] (k contiguous, 384 wide) = W1[k][c]
__global__ void packW1T_kernel(const float* __restrict__ W1, unsigned short* __restrict__ W1T) {
    int i = blockIdx.x * blockDim.x + threadIdx.x;
    if (i >= 128 * 384) return;
    int c = i / 384, k = i - c * 384;
    W1T[i] = f2bf(W1[k * 128 + c]);
}

// ---------------- mean aggregation (bf16 in/out, fp32 accum) ----------------
// one wave per node; lane handles 2 features (4B load per lane = 256B per row)
__global__ void aggregate_bf16_kernel(const unsigned short* __restrict__ h, int ldh,
                                      const int* __restrict__ offs, const int* __restrict__ adj,
                                      unsigned short* __restrict__ m) {
    int node = blockIdx.x * 4 + (threadIdx.x >> 6);
    int lane = threadIdx.x & 63;
    if (node >= N_NODES) return;
    int s = offs[node], e = offs[node + 1];
    float a0 = 0.f, a1 = 0.f;
    int k = s;
    for (; k + 3 < e; k += 4) {
        int s0 = adj[k], s1 = adj[k + 1], s2 = adj[k + 2], s3 = adj[k + 3];
        unsigned int u0 = *(const unsigned int*)(h + (size_t)s0 * ldh + lane * 2);
        unsigned int u1 = *(const unsigned int*)(h + (size_t)s1 * ldh + lane * 2);
        unsigned int u2 = *(const unsigned int*)(h + (size_t)s2 * ldh + lane * 2);
        unsigned int u3 = *(const unsigned int*)(h + (size_t)s3 * ldh + lane * 2);
        a0 += bf2f((unsigned short)u0) + bf2f((unsigned short)u1)
            + bf2f((unsigned short)u2) + bf2f((unsigned short)u3);
        a1 += __uint_as_float(u0 & 0xFFFF0000u) + __uint_as_float(u1 & 0xFFFF0000u)
            + __uint_as_float(u2 & 0xFFFF0000u) + __uint_as_float(u3 & 0xFFFF0000u);
    }
    for (; k < e; ++k) {
        unsigned int u = *(const unsigned int*)(h + (size_t)adj[k] * ldh + lane * 2);
        a0 += bf2f((unsigned short)u);
        a1 += __uint_as_float(u & 0xFFFF0000u);
    }
    float inv = 1.f / fmaxf((float)(e - s), 1.f);
    unsigned int o = ((unsigned int)f2bf(a1 * inv) << 16) | f2bf(a0 * inv);
    *(unsigned int*)(m + (size_t)node * D + lane * 2) = o;
}

// ---------------- SAGE layer: z_slice = bf16(m@Wl + h@Wr + bl) via MFMA ----------------
// 4 waves/block, each wave: 16 rows x 128 cols, K=256 (128 from m, 128 from h)
__global__ void sage_mfma_kernel(const unsigned short* __restrict__ mB,       // [N,128]
                                 const unsigned short* __restrict__ hB, int ldh,
                                 const unsigned short* __restrict__ WT,       // [128][256]
                                 const float* __restrict__ bl,
                                 unsigned short* __restrict__ zout, int ldz) {
    int wid = threadIdx.x >> 6;
    int lane = threadIdx.x & 63;
    int r0 = (blockIdx.x * 4 + wid) * 16;
    int lrow = lane & 15;
    int lk8 = (lane >> 4) * 8;

    f32x4 acc[8];
#pragma unroll
    for (int t = 0; t < 8; ++t) acc[t] = (f32x4){0.f, 0.f, 0.f, 0.f};

    int row = r0 + lrow;
    int rowc = (row < N_NODES) ? row : (N_NODES - 1);
    const unsigned short* aM = mB + (size_t)rowc * D + lk8;
    const unsigned short* aH = hB + (size_t)rowc * ldh + lk8;
    const unsigned short* bBase = WT + (size_t)lrow * 256 + lk8;

#pragma unroll
    for (int kc = 0; kc < 8; ++kc) {
        short8 aF = (kc < 4) ? *(const short8*)(aM + kc * 32)
                             : *(const short8*)(aH + (kc - 4) * 32);
        const unsigned short* bp = bBase + kc * 32;
#pragma unroll
        for (int ct = 0; ct < 8; ++ct) {
            short8 bF = *(const short8*)(bp + ct * 16 * 256);
            acc[ct] = __builtin_amdgcn_mfma_f32_16x16x32_bf16(aF, bF, acc[ct], 0, 0, 0);
        }
    }

    int ocol = lane & 15;
    int orow0 = r0 + (lane >> 4) * 4;
#pragma unroll
    for (int ct = 0; ct < 8; ++ct) {
        float b = bl[ct * 16 + ocol];
#pragma unroll
        for (int j = 0; j < 4; ++j) {
            int orow = orow0 + j;
            if (orow < N_NODES)
                zout[(size_t)orow * ldz + ct * 16 + ocol] = f2bf(acc[ct][j] + b);
        }
    }
}

// ---------------- z1 = bf16(relu(z@W1 + b1)) via MFMA, K=384 ----------------
__global__ void mlp1_mfma_kernel(const unsigned short* __restrict__ zB,   // [N,384]
                                 const unsigned short* __restrict__ W1T,  // [128][384]
                                 const float* __restrict__ b1,
                                 unsigned short* __restrict__ z1) {
    int wid = threadIdx.x >> 6;
    int lane = threadIdx.x & 63;
    int r0 = (blockIdx.x * 4 + wid) * 16;
    int lrow = lane & 15;
    int lk8 = (lane >> 4) * 8;

    f32x4 acc[8];
#pragma unroll
    for (int t = 0; t < 8; ++t) acc[t] = (f32x4){0.f, 0.f, 0.f, 0.f};

    int row = r0 + lrow;
    int rowc = (row < N_NODES) ? row : (N_NODES - 1);
    const unsigned short* aP = zB + (size_t)rowc * DZ + lk8;
    const unsigned short* bBase = W1T + (size_t)lrow * DZ + lk8;

#pragma unroll
    for (int kc = 0; kc < 12; ++kc) {
        short8 aF = *(const short8*)(aP + kc * 32);
        const unsigned short* bp = bBase + kc * 32;
#pragma unroll
        for (int ct = 0; ct < 8; ++ct) {
            short8 bF = *(const short8*)(bp + ct * 16 * DZ);
            acc[ct] = __builtin_amdgcn_mfma_f32_16x16x32_bf16(aF, bF, acc[ct], 0, 0, 0);
        }
    }

    int ocol = lane & 15;
    int orow0 = r0 + (lane >> 4) * 4;
#pragma unroll
    for (int ct = 0; ct < 8; ++ct) {
        float b = b1[ct * 16 + ocol];
#pragma unroll
        for (int j = 0; j < 4; ++j) {
            int orow = orow0 + j;
            if (orow < N_NODES) {
                float v = fmaxf(acc[ct][j] + b, 0.f);
                z1[(size_t)orow * D + ct * 16 + ocol] = f2bf(v);
            }
        }
    }
}

// ---------------- final layer + log_softmax ----------------
__global__ void mlp2_lsm_kernel(const unsigned short* __restrict__ z1,   // [N,128] bf16
                                const float* __restrict__ W2,            // [128,40]
                                const float* __restrict__ b2,
                                float* __restrict__ out) {
    __shared__ float row[128];
    __shared__ float logits[DOUT];
    int n = blockIdx.x;
    int t = threadIdx.x;
    row[t] = bf2f(z1[(size_t)n * D + t]);
    __syncthreads();
    if (t < DOUT) {
        float acc = b2[t];
#pragma unroll 8
        for (int k = 0; k < 128; ++k) acc += row[k] * W2[k * DOUT + t];
        logits[t] = acc;
    }
    __syncthreads();
    if (t < 64) {
        float v = (t < DOUT) ? logits[t] : -1e30f;
        for (int off = 32; off; off >>= 1) v = fmaxf(v, __shfl_down(v, off));
        float mx = __shfl(v, 0);
        float e = (t < DOUT) ? expf(logits[t] - mx) : 0.f;
        float sum = e;
        for (int off = 32; off; off >>= 1) sum += __shfl_down(sum, off);
        float ls = logf(__shfl(sum, 0));
        if (t < DOUT) out[(size_t)n * DOUT + t] = logits[t] - mx - ls;
    }
}

// ---------------- launch ----------------

extern "C" void kernel_launch(void* const* d_in, const int* in_sizes, int n_in,
                              void* d_out, int out_size, void* d_ws, size_t ws_size,
                              hipStream_t stream) {
    const float* x   = (const float*)d_in[0];
    const int*   ei  = (const int*)d_in[1];
    const float* Wl  = (const float*)d_in[2];
    const float* Wr  = (const float*)d_in[3];
    const float* bl  = (const float*)d_in[4];
    const float* W1  = (const float*)d_in[5];
    const float* b1  = (const float*)d_in[6];
    const float* W2  = (const float*)d_in[7];
    const float* b2  = (const float*)d_in[8];
    float* out = (float*)d_out;

    const int E = in_sizes[1] / 2;
    const int* src = ei;
    const int* dst = ei + E;

    // workspace carve-up (256B aligned chunks)
    char* p = (char*)d_ws;
    auto take = [&p](size_t bytes) { char* q = p; p += (bytes + 255) & ~(size_t)255; return q; };
    int* deg    = (int*)take(N_NODES * sizeof(int));
    int* offs   = (int*)take((N_NODES + 1) * sizeof(int));
    int* cursor = (int*)take(N_NODES * sizeof(int));
    int* adj    = (int*)take((size_t)E * sizeof(int));
    unsigned short* xb  = (unsigned short*)take((size_t)N_NODES * D * 2);
    unsigned short* mB  = (unsigned short*)take((size_t)N_NODES * D * 2);
    unsigned short* z   = (unsigned short*)take((size_t)N_NODES * DZ * 2);
    unsigned short* z1  = (unsigned short*)take((size_t)N_NODES * D * 2);
    unsigned short* WT  = (unsigned short*)take((size_t)LAYERS * 128 * 256 * 2);
    unsigned short* W1T = (unsigned short*)take((size_t)128 * 384 * 2);

    hipMemsetAsync(deg, 0, N_NODES * sizeof(int), stream);
    hipMemsetAsync(cursor, 0, N_NODES * sizeof(int), stream);

    // conversions / packing
    int n4 = N_NODES * D / 4;
    cvt_bf16_kernel<<<(n4 + 255) / 256, 256, 0, stream>>>(x, xb, n4);
    packWT_kernel<<<(LAYERS * 128 * 256 + 255) / 256, 256, 0, stream>>>(Wl, Wr, WT);
    packW1T_kernel<<<(128 * 384 + 255) / 256, 256, 0, stream>>>(W1, W1T);

    // CSR
    int egrid = (E + 255) / 256;
    count_deg_kernel<<<egrid, 256, 0, stream>>>(dst, E, deg);
    scan_kernel<<<1, 1024, 0, stream>>>(deg, N_NODES, offs);
    fill_adj_kernel<<<egrid, 256, 0, stream>>>(src, dst, E, offs, cursor, adj);

    int agrid = (N_NODES + 3) / 4;
    int ggrid = (N_NODES + 63) / 64;

    for (int i = 0; i < LAYERS; ++i) {
        const unsigned short* hin = (i == 0) ? xb : (z + (size_t)(i - 1) * D);
        int ldh = (i == 0) ? D : DZ;
        aggregate_bf16_kernel<<<agrid, 256, 0, stream>>>(hin, ldh, offs, adj, mB);
        sage_mfma_kernel<<<ggrid, 256, 0, stream>>>(
            mB, hin, ldh, WT + (size_t)i * 128 * 256, bl + (size_t)i * D,
            z + (size_t)i * D, DZ);
    }

    mlp1_mfma_kernel<<<ggrid, 256, 0, stream>>>(z, W1T, b1, z1);
    mlp2_lsm_kernel<<<N_NODES, 128, 0, stream>>>(z1, W2, b2, out);
}

// Round 3
// 335.565 us; speedup vs baseline: 5.5677x; 1.6069x over previous
//
#include <hip/hip_runtime.h>
#include <math.h>

#define N_NODES 50000
#define D 128
#define LAYERS 3
#define DZ 384
#define DOUT 40

typedef __attribute__((ext_vector_type(4))) float f32x4;
typedef __attribute__((ext_vector_type(8))) short short8;

static __device__ __forceinline__ unsigned short f2bf(float f) {
    unsigned int u = __float_as_uint(f);
    u += 0x7FFFu + ((u >> 16) & 1u);
    return (unsigned short)(u >> 16);
}
static __device__ __forceinline__ float bf2f(unsigned short s) {
    return __uint_as_float(((unsigned int)s) << 16);
}

// ---------------- CSR build ----------------

__global__ void count_deg_kernel(const int* __restrict__ dst, int E, int* __restrict__ deg) {
    int e = blockIdx.x * blockDim.x + threadIdx.x;
    if (e < E) atomicAdd(&deg[dst[e]], 1);
}

// phase 1: per-block (256-wide) sums
__global__ void block_sum_kernel(const int* __restrict__ deg, int n, int* __restrict__ part) {
    __shared__ int s[256];
    int t = threadIdx.x;
    int i = blockIdx.x * 256 + t;
    s[t] = (i < n) ? deg[i] : 0;
    __syncthreads();
    for (int off = 128; off; off >>= 1) {
        if (t < off) s[t] += s[t + off];
        __syncthreads();
    }
    if (t == 0) part[blockIdx.x] = s[0];
}

// phase 2: single-block exclusive scan of partials (nb <= 256)
__global__ void scan_part_kernel(int* __restrict__ part, int nb) {
    __shared__ int s[256];
    int t = threadIdx.x;
    int v = (t < nb) ? part[t] : 0;
    s[t] = v;
    __syncthreads();
    for (int off = 1; off < 256; off <<= 1) {
        int u = (t >= off) ? s[t - off] : 0;
        __syncthreads();
        s[t] += u;
        __syncthreads();
    }
    if (t < nb) part[t] = s[t] - v;  // exclusive
}

// phase 3: per-block exclusive scan + base
__global__ void scan_final_kernel(const int* __restrict__ deg, int n,
                                  const int* __restrict__ part, int* __restrict__ offs, int E) {
    __shared__ int s[256];
    int t = threadIdx.x;
    int i = blockIdx.x * 256 + t;
    int v = (i < n) ? deg[i] : 0;
    s[t] = v;
    __syncthreads();
    for (int off = 1; off < 256; off <<= 1) {
        int u = (t >= off) ? s[t - off] : 0;
        __syncthreads();
        s[t] += u;
        __syncthreads();
    }
    if (i < n) offs[i] = part[blockIdx.x] + s[t] - v;
    if (blockIdx.x == 0 && t == 0) offs[n] = E;
}

__global__ void fill_adj_kernel(const int* __restrict__ src, const int* __restrict__ dst, int E,
                                const int* __restrict__ offs, int* __restrict__ cursor,
                                int* __restrict__ adj) {
    int e = blockIdx.x * blockDim.x + threadIdx.x;
    if (e < E) {
        int d = dst[e];
        int p = atomicAdd(&cursor[d], 1);
        adj[offs[d] + p] = src[e];
    }
}

// ---------------- conversions ----------------

__global__ void cvt_bf16_kernel(const float* __restrict__ in, unsigned short* __restrict__ out, int n4) {
    int i = blockIdx.x * blockDim.x + threadIdx.x;
    if (i >= n4) return;
    const float4 v = ((const float4*)in)[i];
    unsigned int lo = ((unsigned int)f2bf(v.y) << 16) | f2bf(v.x);
    unsigned int hi = ((unsigned int)f2bf(v.w) << 16) | f2bf(v.z);
    ((unsigned int*)out)[i * 2] = lo;
    ((unsigned int*)out)[i * 2 + 1] = hi;
}

// WT[layer][c][k] (k contiguous, 256 wide): k<128 -> Wl[layer][k][c], else Wr[layer][k-128][c]
__global__ void packWT_kernel(const float* __restrict__ Wl, const float* __restrict__ Wr,
                              unsigned short* __restrict__ WT) {
    int i = blockIdx.x * blockDim.x + threadIdx.x;
    if (i >= LAYERS * 128 * 256) return;
    int layer = i >> 15;
    int r = i & 32767;
    int c = r >> 8, k = r & 255;
    const float* W = (k < 128) ? (Wl + layer * 16384) : (Wr + layer * 16384);
    WT[i] = f2bf(W[(k & 127) * 128 + c]);
}

// W1T[c][k] (k contiguous, 384 wide) = W1[k][c]
__global__ void packW1T_kernel(const float* __restrict__ W1, unsigned short* __restrict__ W1T) {
    int i = blockIdx.x * blockDim.x + threadIdx.x;
    if (i >= 128 * 384) return;
    int c = i / 384, k = i - c * 384;
    W1T[i] = f2bf(W1[k * 128 + c]);
}

// W2T[c][k] (k contiguous, 128 wide), c in [0,48), zero-padded past 40
__global__ void packW2T_kernel(const float* __restrict__ W2, unsigned short* __restrict__ W2T) {
    int i = blockIdx.x * blockDim.x + threadIdx.x;
    if (i >= 48 * 128) return;
    int c = i >> 7, k = i & 127;
    W2T[i] = (c < DOUT) ? f2bf(W2[k * DOUT + c]) : (unsigned short)0;
}

// ---------------- mean aggregation (bf16 in/out, fp32 accum) ----------------
// 4 waves/block, wave = 1 node; wave split into 4 groups of 16 lanes,
// each group loads a full 256B row (16B/lane), edges strided across groups.
__global__ __launch_bounds__(256) void aggregate_bf16_kernel(
        const unsigned short* __restrict__ h, int ldh,
        const int* __restrict__ offs, const int* __restrict__ adj,
        unsigned short* __restrict__ m) {
    int node = blockIdx.x * 4 + (threadIdx.x >> 6);
    if (node >= N_NODES) return;
    int lane = threadIdx.x & 63;
    int grp = lane >> 4, l16 = lane & 15;
    int s = offs[node], e = offs[node + 1];

    float acc[8];
#pragma unroll
    for (int j = 0; j < 8; ++j) acc[j] = 0.f;

    int k = s + grp;
    for (; k + 4 < e; k += 8) {
        int s0 = adj[k], s1 = adj[k + 4];
        short8 v0 = *(const short8*)(h + (size_t)s0 * ldh + l16 * 8);
        short8 v1 = *(const short8*)(h + (size_t)s1 * ldh + l16 * 8);
#pragma unroll
        for (int j = 0; j < 8; ++j)
            acc[j] += bf2f((unsigned short)v0[j]) + bf2f((unsigned short)v1[j]);
    }
    if (k < e) {
        int s0 = adj[k];
        short8 v0 = *(const short8*)(h + (size_t)s0 * ldh + l16 * 8);
#pragma unroll
        for (int j = 0; j < 8; ++j) acc[j] += bf2f((unsigned short)v0[j]);
    }

    // reduce across the 4 groups
#pragma unroll
    for (int j = 0; j < 8; ++j) {
        float a = acc[j];
        a += __shfl_xor(a, 16);
        a += __shfl_xor(a, 32);
        acc[j] = a;
    }

    if (grp == 0) {
        float inv = 1.f / fmaxf((float)(e - s), 1.f);
        uint4 o;
        o.x = ((unsigned int)f2bf(acc[1] * inv) << 16) | f2bf(acc[0] * inv);
        o.y = ((unsigned int)f2bf(acc[3] * inv) << 16) | f2bf(acc[2] * inv);
        o.z = ((unsigned int)f2bf(acc[5] * inv) << 16) | f2bf(acc[4] * inv);
        o.w = ((unsigned int)f2bf(acc[7] * inv) << 16) | f2bf(acc[6] * inv);
        *(uint4*)(m + (size_t)node * D + l16 * 8) = o;
    }
}

// ---------------- SAGE layer: z_slice = bf16(m@Wl + h@Wr + bl), 32 rows/wave ----------------
__global__ __launch_bounds__(256) void sage_mfma_kernel(
        const unsigned short* __restrict__ mB,
        const unsigned short* __restrict__ hB, int ldh,
        const unsigned short* __restrict__ WT,   // [128][256]
        const float* __restrict__ bl,
        unsigned short* __restrict__ zout, int ldz) {
    int wid = threadIdx.x >> 6;
    int lane = threadIdx.x & 63;
    int r0 = (blockIdx.x * 4 + wid) * 32;
    int lrow = lane & 15;
    int lk8 = (lane >> 4) * 8;

    f32x4 acc0[8], acc1[8];
#pragma unroll
    for (int t = 0; t < 8; ++t) { acc0[t] = (f32x4){0.f,0.f,0.f,0.f}; acc1[t] = (f32x4){0.f,0.f,0.f,0.f}; }

    int rA = r0 + lrow, rB = r0 + 16 + lrow;
    int rAc = (rA < N_NODES) ? rA : (N_NODES - 1);
    int rBc = (rB < N_NODES) ? rB : (N_NODES - 1);
    const unsigned short* aM0 = mB + (size_t)rAc * D + lk8;
    const unsigned short* aM1 = mB + (size_t)rBc * D + lk8;
    const unsigned short* aH0 = hB + (size_t)rAc * ldh + lk8;
    const unsigned short* aH1 = hB + (size_t)rBc * ldh + lk8;
    const unsigned short* bBase = WT + (size_t)lrow * 256 + lk8;

#pragma unroll
    for (int kc = 0; kc < 8; ++kc) {
        short8 aF0 = (kc < 4) ? *(const short8*)(aM0 + kc * 32)
                              : *(const short8*)(aH0 + (kc - 4) * 32);
        short8 aF1 = (kc < 4) ? *(const short8*)(aM1 + kc * 32)
                              : *(const short8*)(aH1 + (kc - 4) * 32);
        const unsigned short* bp = bBase + kc * 32;
#pragma unroll
        for (int ct = 0; ct < 8; ++ct) {
            short8 bF = *(const short8*)(bp + ct * 16 * 256);
            acc0[ct] = __builtin_amdgcn_mfma_f32_16x16x32_bf16(aF0, bF, acc0[ct], 0, 0, 0);
            acc1[ct] = __builtin_amdgcn_mfma_f32_16x16x32_bf16(aF1, bF, acc1[ct], 0, 0, 0);
        }
    }

    int ocol = lane & 15;
    int orow0 = r0 + (lane >> 4) * 4;
#pragma unroll
    for (int ct = 0; ct < 8; ++ct) {
        float b = bl[ct * 16 + ocol];
#pragma unroll
        for (int j = 0; j < 4; ++j) {
            int ra = orow0 + j;
            int rb = ra + 16;
            if (ra < N_NODES) zout[(size_t)ra * ldz + ct * 16 + ocol] = f2bf(acc0[ct][j] + b);
            if (rb < N_NODES) zout[(size_t)rb * ldz + ct * 16 + ocol] = f2bf(acc1[ct][j] + b);
        }
    }
}

// ---------------- z1 = bf16(relu(z@W1 + b1)), K=384, 32 rows/wave ----------------
__global__ __launch_bounds__(256) void mlp1_mfma_kernel(
        const unsigned short* __restrict__ zB,   // [N,384]
        const unsigned short* __restrict__ W1T,  // [128][384]
        const float* __restrict__ b1,
        unsigned short* __restrict__ z1) {
    int wid = threadIdx.x >> 6;
    int lane = threadIdx.x & 63;
    int r0 = (blockIdx.x * 4 + wid) * 32;
    int lrow = lane & 15;
    int lk8 = (lane >> 4) * 8;

    f32x4 acc0[8], acc1[8];
#pragma unroll
    for (int t = 0; t < 8; ++t) { acc0[t] = (f32x4){0.f,0.f,0.f,0.f}; acc1[t] = (f32x4){0.f,0.f,0.f,0.f}; }

    int rA = r0 + lrow, rB = r0 + 16 + lrow;
    int rAc = (rA < N_NODES) ? rA : (N_NODES - 1);
    int rBc = (rB < N_NODES) ? rB : (N_NODES - 1);
    const unsigned short* aP0 = zB + (size_t)rAc * DZ + lk8;
    const unsigned short* aP1 = zB + (size_t)rBc * DZ + lk8;
    const unsigned short* bBase = W1T + (size_t)lrow * DZ + lk8;

#pragma unroll
    for (int kc = 0; kc < 12; ++kc) {
        short8 aF0 = *(const short8*)(aP0 + kc * 32);
        short8 aF1 = *(const short8*)(aP1 + kc * 32);
        const unsigned short* bp = bBase + kc * 32;
#pragma unroll
        for (int ct = 0; ct < 8; ++ct) {
            short8 bF = *(const short8*)(bp + ct * 16 * DZ);
            acc0[ct] = __builtin_amdgcn_mfma_f32_16x16x32_bf16(aF0, bF, acc0[ct], 0, 0, 0);
            acc1[ct] = __builtin_amdgcn_mfma_f32_16x16x32_bf16(aF1, bF, acc1[ct], 0, 0, 0);
        }
    }

    int ocol = lane & 15;
    int orow0 = r0 + (lane >> 4) * 4;
#pragma unroll
    for (int ct = 0; ct < 8; ++ct) {
        float b = b1[ct * 16 + ocol];
#pragma unroll
        for (int j = 0; j < 4; ++j) {
            int ra = orow0 + j;
            int rb = ra + 16;
            if (ra < N_NODES) z1[(size_t)ra * D + ct * 16 + ocol] = f2bf(fmaxf(acc0[ct][j] + b, 0.f));
            if (rb < N_NODES) z1[(size_t)rb * D + ct * 16 + ocol] = f2bf(fmaxf(acc1[ct][j] + b, 0.f));
        }
    }
}

// ---------------- final layer + log_softmax via MFMA ----------------
// wave = 16 rows x 48 cols (40 valid), K=128; softmax across 16-lane group
__global__ __launch_bounds__(256) void mlp2_lsm_mfma_kernel(
        const unsigned short* __restrict__ z1,   // [N,128] bf16
        const unsigned short* __restrict__ W2T,  // [48][128] bf16
        const float* __restrict__ b2,
        float* __restrict__ out) {
    int wid = threadIdx.x >> 6;
    int lane = threadIdx.x & 63;
    int r0 = (blockIdx.x * 4 + wid) * 16;
    int lrow = lane & 15;
    int lk8 = (lane >> 4) * 8;

    f32x4 acc[3];
#pragma unroll
    for (int t = 0; t < 3; ++t) acc[t] = (f32x4){0.f,0.f,0.f,0.f};

    int row = r0 + lrow;
    int rowc = (row < N_NODES) ? row : (N_NODES - 1);
    const unsigned short* aP = z1 + (size_t)rowc * D + lk8;
    const unsigned short* bBase = W2T + (size_t)lrow * D + lk8;

#pragma unroll
    for (int kc = 0; kc < 4; ++kc) {
        short8 aF = *(const short8*)(aP + kc * 32);
        const unsigned short* bp = bBase + kc * 32;
#pragma unroll
        for (int ct = 0; ct < 3; ++ct) {
            short8 bF = *(const short8*)(bp + ct * 16 * D);
            acc[ct] = __builtin_amdgcn_mfma_f32_16x16x32_bf16(aF, bF, acc[ct], 0, 0, 0);
        }
    }

    int ocol = lane & 15;
    float b0 = b2[ocol];
    float b1v = b2[16 + ocol];
    float b2v = (ocol < 8) ? b2[32 + ocol] : 0.f;

#pragma unroll
    for (int j = 0; j < 4; ++j) {
        int orow = r0 + (lane >> 4) * 4 + j;
        float v0 = acc[0][j] + b0;
        float v1 = acc[1][j] + b1v;
        float v2 = (ocol < 8) ? (acc[2][j] + b2v) : -1e30f;
        float mx = fmaxf(fmaxf(v0, v1), v2);
        mx = fmaxf(mx, __shfl_xor(mx, 1));
        mx = fmaxf(mx, __shfl_xor(mx, 2));
        mx = fmaxf(mx, __shfl_xor(mx, 4));
        mx = fmaxf(mx, __shfl_xor(mx, 8));
        float es = expf(v0 - mx) + expf(v1 - mx) + ((ocol < 8) ? expf(v2 - mx) : 0.f);
        es += __shfl_xor(es, 1);
        es += __shfl_xor(es, 2);
        es += __shfl_xor(es, 4);
        es += __shfl_xor(es, 8);
        float ls = logf(es);
        if (orow < N_NODES) {
            out[(size_t)orow * DOUT + ocol] = v0 - mx - ls;
            out[(size_t)orow * DOUT + 16 + ocol] = v1 - mx - ls;
            if (ocol < 8) out[(size_t)orow * DOUT + 32 + ocol] = v2 - mx - ls;
        }
    }
}

// ---------------- launch ----------------

extern "C" void kernel_launch(void* const* d_in, const int* in_sizes, int n_in,
                              void* d_out, int out_size, void* d_ws, size_t ws_size,
                              hipStream_t stream) {
    const float* x   = (const float*)d_in[0];
    const int*   ei  = (const int*)d_in[1];
    const float* Wl  = (const float*)d_in[2];
    const float* Wr  = (const float*)d_in[3];
    const float* bl  = (const float*)d_in[4];
    const float* W1  = (const float*)d_in[5];
    const float* b1  = (const float*)d_in[6];
    const float* W2  = (const float*)d_in[7];
    const float* b2  = (const float*)d_in[8];
    float* out = (float*)d_out;

    const int E = in_sizes[1] / 2;
    const int* src = ei;
    const int* dst = ei + E;

    char* p = (char*)d_ws;
    auto take = [&p](size_t bytes) { char* q = p; p += (bytes + 255) & ~(size_t)255; return q; };
    int* deg    = (int*)take(N_NODES * sizeof(int));
    int* offs   = (int*)take((N_NODES + 1) * sizeof(int));
    int* cursor = (int*)take(N_NODES * sizeof(int));
    int* part   = (int*)take(256 * sizeof(int));
    int* adj    = (int*)take((size_t)E * sizeof(int));
    unsigned short* xb  = (unsigned short*)take((size_t)N_NODES * D * 2);
    unsigned short* mB  = (unsigned short*)take((size_t)N_NODES * D * 2);
    unsigned short* z   = (unsigned short*)take((size_t)N_NODES * DZ * 2);
    unsigned short* z1  = (unsigned short*)take((size_t)N_NODES * D * 2);
    unsigned short* WT  = (unsigned short*)take((size_t)LAYERS * 128 * 256 * 2);
    unsigned short* W1T = (unsigned short*)take((size_t)128 * 384 * 2);
    unsigned short* W2T = (unsigned short*)take((size_t)48 * 128 * 2);

    hipMemsetAsync(deg, 0, N_NODES * sizeof(int), stream);
    hipMemsetAsync(cursor, 0, N_NODES * sizeof(int), stream);

    // conversions / packing
    int n4 = N_NODES * D / 4;
    cvt_bf16_kernel<<<(n4 + 255) / 256, 256, 0, stream>>>(x, xb, n4);
    packWT_kernel<<<(LAYERS * 128 * 256 + 255) / 256, 256, 0, stream>>>(Wl, Wr, WT);
    packW1T_kernel<<<(128 * 384 + 255) / 256, 256, 0, stream>>>(W1, W1T);
    packW2T_kernel<<<(48 * 128 + 255) / 256, 256, 0, stream>>>(W2, W2T);

    // CSR
    int egrid = (E + 255) / 256;
    int nb = (N_NODES + 255) / 256;          // 196
    count_deg_kernel<<<egrid, 256, 0, stream>>>(dst, E, deg);
    block_sum_kernel<<<nb, 256, 0, stream>>>(deg, N_NODES, part);
    scan_part_kernel<<<1, 256, 0, stream>>>(part, nb);
    scan_final_kernel<<<nb, 256, 0, stream>>>(deg, N_NODES, part, offs, E);
    fill_adj_kernel<<<egrid, 256, 0, stream>>>(src, dst, E, offs, cursor, adj);

    int agrid = (N_NODES + 3) / 4;
    int ggrid = (N_NODES + 127) / 128;       // 32 rows/wave, 4 waves
    int g16   = (N_NODES + 63) / 64;         // 16 rows/wave, 4 waves

    for (int i = 0; i < LAYERS; ++i) {
        const unsigned short* hin = (i == 0) ? xb : (z + (size_t)(i - 1) * D);
        int ldh = (i == 0) ? D : DZ;
        aggregate_bf16_kernel<<<agrid, 256, 0, stream>>>(hin, ldh, offs, adj, mB);
        sage_mfma_kernel<<<ggrid, 256, 0, stream>>>(
            mB, hin, ldh, WT + (size_t)i * 128 * 256, bl + (size_t)i * D,
            z + (size_t)i * D, DZ);
    }

    mlp1_mfma_kernel<<<ggrid, 256, 0, stream>>>(z, W1T, b1, z1);
    mlp2_lsm_mfma_kernel<<<g16, 256, 0, stream>>>(z1, W2T, b2, out);
}

// Round 5
// 275.419 us; speedup vs baseline: 6.7836x; 1.2184x over previous
//
#include <hip/hip_runtime.h>
#include <math.h>

#define N_NODES 50000
#define D 128
#define LAYERS 3
#define DZ 384
#define DOUT 40
#define BUCKETS 196          // ceil(50000/256)

typedef __attribute__((ext_vector_type(4))) float f32x4;
typedef __attribute__((ext_vector_type(8))) short short8;

static __device__ __forceinline__ unsigned short f2bf(float f) {
    unsigned int u = __float_as_uint(f);
    u += 0x7FFFu + ((u >> 16) & 1u);
    return (unsigned short)(u >> 16);
}
static __device__ __forceinline__ float bf2f(unsigned short s) {
    return __uint_as_float(((unsigned int)s) << 16);
}

// ---------------- CSR build: atomic-free two-level counting sort ----------------

// K1: per-block LDS histogram over dst>>8 buckets
__global__ __launch_bounds__(256) void hist1_kernel(const int* __restrict__ dst, int E, int CH,
                                                    int nblk1, int* __restrict__ H) {
    __shared__ int h[BUCKETS];
    int t = threadIdx.x;
    if (t < BUCKETS) h[t] = 0;
    __syncthreads();
    int s = blockIdx.x * CH, e = min(E, s + CH);
    for (int i = s + t; i < e; i += 256) atomicAdd(&h[dst[i] >> 8], 1);
    __syncthreads();
    if (t < BUCKETS) H[t * nblk1 + blockIdx.x] = h[t];
}

// K2: per-bucket exclusive scan over blocks (in-place), total -> T
__global__ __launch_bounds__(512) void scanS_kernel(int* __restrict__ H, int nblk1,
                                                    int* __restrict__ T) {
    __shared__ int s[512];
    int t = threadIdx.x, k = blockIdx.x;
    int v = (t < nblk1) ? H[k * nblk1 + t] : 0;
    s[t] = v;
    __syncthreads();
    for (int off = 1; off < 512; off <<= 1) {
        int u = (t >= off) ? s[t - off] : 0;
        __syncthreads();
        s[t] += u;
        __syncthreads();
    }
    if (t < nblk1) H[k * nblk1 + t] = s[t] - v;
    if (t == 511) T[k] = s[511];
}

// K3: scan bucket totals -> bucketStart
__global__ __launch_bounds__(256) void bstart_kernel(const int* __restrict__ T,
                                                     int* __restrict__ bucketStart,
                                                     int* __restrict__ offs, int E) {
    __shared__ int s[256];
    int t = threadIdx.x;
    int v = (t < BUCKETS) ? T[t] : 0;
    s[t] = v;
    __syncthreads();
    for (int off = 1; off < 256; off <<= 1) {
        int u = (t >= off) ? s[t - off] : 0;
        __syncthreads();
        s[t] += u;
        __syncthreads();
    }
    if (t < BUCKETS) bucketStart[t] = s[t] - v;
    if (t == 0) { bucketStart[BUCKETS] = E; offs[N_NODES] = E; }
}

// K5: scatter packed records (src:u16 | dlo:u8<<16) into contiguous (block,bucket) runs
__global__ __launch_bounds__(256) void scatter_kernel(const int* __restrict__ src,
                                                      const int* __restrict__ dst, int E, int CH,
                                                      int nblk1, const int* __restrict__ H,
                                                      const int* __restrict__ bucketStart,
                                                      unsigned int* __restrict__ recs) {
    __shared__ int cur[BUCKETS];
    int t = threadIdx.x;
    if (t < BUCKETS) cur[t] = bucketStart[t] + H[t * nblk1 + blockIdx.x];
    __syncthreads();
    int s = blockIdx.x * CH, e = min(E, s + CH);
    for (int i = s + t; i < e; i += 256) {
        int d = dst[i];
        int pos = atomicAdd(&cur[d >> 8], 1);
        recs[pos] = (unsigned int)(src[i] & 0xFFFF) | ((unsigned int)(d & 255) << 16);
    }
}

// K6: per-bucket local CSR: offs + u16 adj
__global__ __launch_bounds__(256) void bucket_csr_kernel(const unsigned int* __restrict__ recs,
                                                         const int* __restrict__ bucketStart,
                                                         int* __restrict__ offs,
                                                         unsigned short* __restrict__ adj) {
    __shared__ int h[256];
    __shared__ int sc[256];
    __shared__ int cur[256];
    int t = threadIdx.x, k = blockIdx.x;
    int bs = bucketStart[k], be = bucketStart[k + 1];
    h[t] = 0;
    __syncthreads();
    for (int i = bs + t; i < be; i += 256) atomicAdd(&h[(recs[i] >> 16) & 255], 1);
    __syncthreads();
    int v = h[t];
    sc[t] = v;
    __syncthreads();
    for (int off = 1; off < 256; off <<= 1) {
        int u = (t >= off) ? sc[t - off] : 0;
        __syncthreads();
        sc[t] += u;
        __syncthreads();
    }
    int excl = sc[t] - v;
    int node = k * 256 + t;
    if (node < N_NODES) offs[node] = bs + excl;
    cur[t] = bs + excl;
    __syncthreads();
    for (int i = bs + t; i < be; i += 256) {
        unsigned int r = recs[i];
        int pos = atomicAdd(&cur[(r >> 16) & 255], 1);
        adj[pos] = (unsigned short)(r & 0xFFFF);
    }
}

// ---------------- conversions ----------------

__global__ void cvt_bf16_kernel(const float* __restrict__ in, unsigned short* __restrict__ out, int n4) {
    int i = blockIdx.x * blockDim.x + threadIdx.x;
    if (i >= n4) return;
    const float4 v = ((const float4*)in)[i];
    unsigned int lo = ((unsigned int)f2bf(v.y) << 16) | f2bf(v.x);
    unsigned int hi = ((unsigned int)f2bf(v.w) << 16) | f2bf(v.z);
    ((unsigned int*)out)[i * 2] = lo;
    ((unsigned int*)out)[i * 2 + 1] = hi;
}

// WT[layer][c][k] (k contiguous, 256 wide): k<128 -> Wl[layer][k][c], else Wr[layer][k-128][c]
__global__ void packWT_kernel(const float* __restrict__ Wl, const float* __restrict__ Wr,
                              unsigned short* __restrict__ WT) {
    int i = blockIdx.x * blockDim.x + threadIdx.x;
    if (i >= LAYERS * 128 * 256) return;
    int layer = i >> 15;
    int r = i & 32767;
    int c = r >> 8, k = r & 255;
    const float* W = (k < 128) ? (Wl + layer * 16384) : (Wr + layer * 16384);
    WT[i] = f2bf(W[(k & 127) * 128 + c]);
}

__global__ void packW1T_kernel(const float* __restrict__ W1, unsigned short* __restrict__ W1T) {
    int i = blockIdx.x * blockDim.x + threadIdx.x;
    if (i >= 128 * 384) return;
    int c = i / 384, k = i - c * 384;
    W1T[i] = f2bf(W1[k * 128 + c]);
}

__global__ void packW2T_kernel(const float* __restrict__ W2, unsigned short* __restrict__ W2T) {
    int i = blockIdx.x * blockDim.x + threadIdx.x;
    if (i >= 48 * 128) return;
    int c = i >> 7, k = i & 127;
    W2T[i] = (c < DOUT) ? f2bf(W2[k * DOUT + c]) : (unsigned short)0;
}

// ---------------- mean aggregation (bf16 in/out, fp32 accum) ----------------
__global__ __launch_bounds__(256) void aggregate_bf16_kernel(
        const unsigned short* __restrict__ h, int ldh,
        const int* __restrict__ offs, const unsigned short* __restrict__ adj,
        unsigned short* __restrict__ m) {
    int node = blockIdx.x * 4 + (threadIdx.x >> 6);
    if (node >= N_NODES) return;
    int lane = threadIdx.x & 63;
    int grp = lane >> 4, l16 = lane & 15;
    int s = offs[node], e = offs[node + 1];

    float acc[8];
#pragma unroll
    for (int j = 0; j < 8; ++j) acc[j] = 0.f;

    int k = s + grp;
    for (; k + 4 < e; k += 8) {
        int s0 = adj[k], s1 = adj[k + 4];
        short8 v0 = *(const short8*)(h + (size_t)s0 * ldh + l16 * 8);
        short8 v1 = *(const short8*)(h + (size_t)s1 * ldh + l16 * 8);
#pragma unroll
        for (int j = 0; j < 8; ++j)
            acc[j] += bf2f((unsigned short)v0[j]) + bf2f((unsigned short)v1[j]);
    }
    if (k < e) {
        int s0 = adj[k];
        short8 v0 = *(const short8*)(h + (size_t)s0 * ldh + l16 * 8);
#pragma unroll
        for (int j = 0; j < 8; ++j) acc[j] += bf2f((unsigned short)v0[j]);
    }

#pragma unroll
    for (int j = 0; j < 8; ++j) {
        float a = acc[j];
        a += __shfl_xor(a, 16);
        a += __shfl_xor(a, 32);
        acc[j] = a;
    }

    if (grp == 0) {
        float inv = 1.f / fmaxf((float)(e - s), 1.f);
        uint4 o;
        o.x = ((unsigned int)f2bf(acc[1] * inv) << 16) | f2bf(acc[0] * inv);
        o.y = ((unsigned int)f2bf(acc[3] * inv) << 16) | f2bf(acc[2] * inv);
        o.z = ((unsigned int)f2bf(acc[5] * inv) << 16) | f2bf(acc[4] * inv);
        o.w = ((unsigned int)f2bf(acc[7] * inv) << 16) | f2bf(acc[6] * inv);
        *(uint4*)(m + (size_t)node * D + l16 * 8) = o;
    }
}

// ---------------- SAGE layer: z_slice = bf16(m@Wl + h@Wr + bl), 32 rows/wave ----------------
__global__ __launch_bounds__(256) void sage_mfma_kernel(
        const unsigned short* __restrict__ mB,
        const unsigned short* __restrict__ hB, int ldh,
        const unsigned short* __restrict__ WT,   // [128][256]
        const float* __restrict__ bl,
        unsigned short* __restrict__ zout, int ldz) {
    int wid = threadIdx.x >> 6;
    int lane = threadIdx.x & 63;
    int r0 = (blockIdx.x * 4 + wid) * 32;
    int lrow = lane & 15;
    int lk8 = (lane >> 4) * 8;

    f32x4 acc0[8], acc1[8];
#pragma unroll
    for (int t = 0; t < 8; ++t) { acc0[t] = (f32x4){0.f,0.f,0.f,0.f}; acc1[t] = (f32x4){0.f,0.f,0.f,0.f}; }

    int rA = r0 + lrow, rB = r0 + 16 + lrow;
    int rAc = (rA < N_NODES) ? rA : (N_NODES - 1);
    int rBc = (rB < N_NODES) ? rB : (N_NODES - 1);
    const unsigned short* aM0 = mB + (size_t)rAc * D + lk8;
    const unsigned short* aM1 = mB + (size_t)rBc * D + lk8;
    const unsigned short* aH0 = hB + (size_t)rAc * ldh + lk8;
    const unsigned short* aH1 = hB + (size_t)rBc * ldh + lk8;
    const unsigned short* bBase = WT + (size_t)lrow * 256 + lk8;

#pragma unroll
    for (int kc = 0; kc < 8; ++kc) {
        short8 aF0 = (kc < 4) ? *(const short8*)(aM0 + kc * 32)
                              : *(const short8*)(aH0 + (kc - 4) * 32);
        short8 aF1 = (kc < 4) ? *(const short8*)(aM1 + kc * 32)
                              : *(const short8*)(aH1 + (kc - 4) * 32);
        const unsigned short* bp = bBase + kc * 32;
#pragma unroll
        for (int ct = 0; ct < 8; ++ct) {
            short8 bF = *(const short8*)(bp + ct * 16 * 256);
            acc0[ct] = __builtin_amdgcn_mfma_f32_16x16x32_bf16(aF0, bF, acc0[ct], 0, 0, 0);
            acc1[ct] = __builtin_amdgcn_mfma_f32_16x16x32_bf16(aF1, bF, acc1[ct], 0, 0, 0);
        }
    }

    int ocol = lane & 15;
    int orow0 = r0 + (lane >> 4) * 4;
#pragma unroll
    for (int ct = 0; ct < 8; ++ct) {
        float b = bl[ct * 16 + ocol];
#pragma unroll
        for (int j = 0; j < 4; ++j) {
            int ra = orow0 + j;
            int rb = ra + 16;
            if (ra < N_NODES) zout[(size_t)ra * ldz + ct * 16 + ocol] = f2bf(acc0[ct][j] + b);
            if (rb < N_NODES) zout[(size_t)rb * ldz + ct * 16 + ocol] = f2bf(acc1[ct][j] + b);
        }
    }
}

// ---------------- z1 = bf16(relu(z@W1 + b1)), K=384, 32 rows/wave ----------------
__global__ __launch_bounds__(256) void mlp1_mfma_kernel(
        const unsigned short* __restrict__ zB,   // [N,384]
        const unsigned short* __restrict__ W1T,  // [128][384]
        const float* __restrict__ b1,
        unsigned short* __restrict__ z1) {
    int wid = threadIdx.x >> 6;
    int lane = threadIdx.x & 63;
    int r0 = (blockIdx.x * 4 + wid) * 32;
    int lrow = lane & 15;
    int lk8 = (lane >> 4) * 8;

    f32x4 acc0[8], acc1[8];
#pragma unroll
    for (int t = 0; t < 8; ++t) { acc0[t] = (f32x4){0.f,0.f,0.f,0.f}; acc1[t] = (f32x4){0.f,0.f,0.f,0.f}; }

    int rA = r0 + lrow, rB = r0 + 16 + lrow;
    int rAc = (rA < N_NODES) ? rA : (N_NODES - 1);
    int rBc = (rB < N_NODES) ? rB : (N_NODES - 1);
    const unsigned short* aP0 = zB + (size_t)rAc * DZ + lk8;
    const unsigned short* aP1 = zB + (size_t)rBc * DZ + lk8;
    const unsigned short* bBase = W1T + (size_t)lrow * DZ + lk8;

#pragma unroll
    for (int kc = 0; kc < 12; ++kc) {
        short8 aF0 = *(const short8*)(aP0 + kc * 32);
        short8 aF1 = *(const short8*)(aP1 + kc * 32);
        const unsigned short* bp = bBase + kc * 32;
#pragma unroll
        for (int ct = 0; ct < 8; ++ct) {
            short8 bF = *(const short8*)(bp + ct * 16 * DZ);
            acc0[ct] = __builtin_amdgcn_mfma_f32_16x16x32_bf16(aF0, bF, acc0[ct], 0, 0, 0);
            acc1[ct] = __builtin_amdgcn_mfma_f32_16x16x32_bf16(aF1, bF, acc1[ct], 0, 0, 0);
        }
    }

    int ocol = lane & 15;
    int orow0 = r0 + (lane >> 4) * 4;
#pragma unroll
    for (int ct = 0; ct < 8; ++ct) {
        float b = b1[ct * 16 + ocol];
#pragma unroll
        for (int j = 0; j < 4; ++j) {
            int ra = orow0 + j;
            int rb = ra + 16;
            if (ra < N_NODES) z1[(size_t)ra * D + ct * 16 + ocol] = f2bf(fmaxf(acc0[ct][j] + b, 0.f));
            if (rb < N_NODES) z1[(size_t)rb * D + ct * 16 + ocol] = f2bf(fmaxf(acc1[ct][j] + b, 0.f));
        }
    }
}

// ---------------- final layer + log_softmax via MFMA ----------------
__global__ __launch_bounds__(256) void mlp2_lsm_mfma_kernel(
        const unsigned short* __restrict__ z1,   // [N,128] bf16
        const unsigned short* __restrict__ W2T,  // [48][128] bf16
        const float* __restrict__ b2,
        float* __restrict__ out) {
    int wid = threadIdx.x >> 6;
    int lane = threadIdx.x & 63;
    int r0 = (blockIdx.x * 4 + wid) * 16;
    int lrow = lane & 15;
    int lk8 = (lane >> 4) * 8;

    f32x4 acc[3];
#pragma unroll
    for (int t = 0; t < 3; ++t) acc[t] = (f32x4){0.f,0.f,0.f,0.f};

    int row = r0 + lrow;
    int rowc = (row < N_NODES) ? row : (N_NODES - 1);
    const unsigned short* aP = z1 + (size_t)rowc * D + lk8;
    const unsigned short* bBase = W2T + (size_t)lrow * D + lk8;

#pragma unroll
    for (int kc = 0; kc < 4; ++kc) {
        short8 aF = *(const short8*)(aP + kc * 32);
        const unsigned short* bp = bBase + kc * 32;
#pragma unroll
        for (int ct = 0; ct < 3; ++ct) {
            short8 bF = *(const short8*)(bp + ct * 16 * D);
            acc[ct] = __builtin_amdgcn_mfma_f32_16x16x32_bf16(aF, bF, acc[ct], 0, 0, 0);
        }
    }

    int ocol = lane & 15;
    float b0 = b2[ocol];
    float b1v = b2[16 + ocol];
    float b2v = (ocol < 8) ? b2[32 + ocol] : 0.f;

#pragma unroll
    for (int j = 0; j < 4; ++j) {
        int orow = r0 + (lane >> 4) * 4 + j;
        float v0 = acc[0][j] + b0;
        float v1 = acc[1][j] + b1v;
        float v2 = (ocol < 8) ? (acc[2][j] + b2v) : -1e30f;
        float mx = fmaxf(fmaxf(v0, v1), v2);
        mx = fmaxf(mx, __shfl_xor(mx, 1));
        mx = fmaxf(mx, __shfl_xor(mx, 2));
        mx = fmaxf(mx, __shfl_xor(mx, 4));
        mx = fmaxf(mx, __shfl_xor(mx, 8));
        float es = expf(v0 - mx) + expf(v1 - mx) + ((ocol < 8) ? expf(v2 - mx) : 0.f);
        es += __shfl_xor(es, 1);
        es += __shfl_xor(es, 2);
        es += __shfl_xor(es, 4);
        es += __shfl_xor(es, 8);
        float ls = logf(es);
        if (orow < N_NODES) {
            out[(size_t)orow * DOUT + ocol] = v0 - mx - ls;
            out[(size_t)orow * DOUT + 16 + ocol] = v1 - mx - ls;
            if (ocol < 8) out[(size_t)orow * DOUT + 32 + ocol] = v2 - mx - ls;
        }
    }
}

// ---------------- launch ----------------

extern "C" void kernel_launch(void* const* d_in, const int* in_sizes, int n_in,
                              void* d_out, int out_size, void* d_ws, size_t ws_size,
                              hipStream_t stream) {
    const float* x   = (const float*)d_in[0];
    const int*   ei  = (const int*)d_in[1];
    const float* Wl  = (const float*)d_in[2];
    const float* Wr  = (const float*)d_in[3];
    const float* bl  = (const float*)d_in[4];
    const float* W1  = (const float*)d_in[5];
    const float* b1  = (const float*)d_in[6];
    const float* W2  = (const float*)d_in[7];
    const float* b2  = (const float*)d_in[8];
    float* out = (float*)d_out;

    const int E = in_sizes[1] / 2;
    const int* src = ei;
    const int* dst = ei + E;

    int CH = 2048;
    int nblk1 = (E + CH - 1) / CH;
    if (nblk1 > 512) { CH = ((E + 511) / 512 + 255) & ~255; nblk1 = (E + CH - 1) / CH; }

    char* p = (char*)d_ws;
    auto take = [&p](size_t bytes) { char* q = p; p += (bytes + 255) & ~(size_t)255; return q; };
    int* offs        = (int*)take((N_NODES + 1) * sizeof(int));
    int* H           = (int*)take((size_t)BUCKETS * nblk1 * sizeof(int));
    int* T           = (int*)take(BUCKETS * sizeof(int));
    int* bucketStart = (int*)take((BUCKETS + 1) * sizeof(int));
    unsigned int*   recs = (unsigned int*)take((size_t)E * sizeof(unsigned int));
    unsigned short* adj  = (unsigned short*)take((size_t)E * sizeof(unsigned short));
    unsigned short* xb  = (unsigned short*)take((size_t)N_NODES * D * 2);
    unsigned short* mB  = (unsigned short*)take((size_t)N_NODES * D * 2);
    unsigned short* z   = (unsigned short*)take((size_t)N_NODES * DZ * 2);
    unsigned short* z1  = (unsigned short*)take((size_t)N_NODES * D * 2);
    unsigned short* WT  = (unsigned short*)take((size_t)LAYERS * 128 * 256 * 2);
    unsigned short* W1T = (unsigned short*)take((size_t)128 * 384 * 2);
    unsigned short* W2T = (unsigned short*)take((size_t)48 * 128 * 2);

    // conversions / packing
    int n4 = N_NODES * D / 4;
    cvt_bf16_kernel<<<(n4 + 255) / 256, 256, 0, stream>>>(x, xb, n4);
    packWT_kernel<<<(LAYERS * 128 * 256 + 255) / 256, 256, 0, stream>>>(Wl, Wr, WT);
    packW1T_kernel<<<(128 * 384 + 255) / 256, 256, 0, stream>>>(W1, W1T);
    packW2T_kernel<<<(48 * 128 + 255) / 256, 256, 0, stream>>>(W2, W2T);

    // CSR via counting sort (no global atomics)
    hist1_kernel<<<nblk1, 256, 0, stream>>>(dst, E, CH, nblk1, H);
    scanS_kernel<<<BUCKETS, 512, 0, stream>>>(H, nblk1, T);
    bstart_kernel<<<1, 256, 0, stream>>>(T, bucketStart, offs, E);
    scatter_kernel<<<nblk1, 256, 0, stream>>>(src, dst, E, CH, nblk1, H, bucketStart, recs);
    bucket_csr_kernel<<<BUCKETS, 256, 0, stream>>>(recs, bucketStart, offs, adj);

    int agrid = (N_NODES + 3) / 4;
    int ggrid = (N_NODES + 127) / 128;
    int g16   = (N_NODES + 63) / 64;

    for (int i = 0; i < LAYERS; ++i) {
        const unsigned short* hin = (i == 0) ? xb : (z + (size_t)(i - 1) * D);
        int ldh = (i == 0) ? D : DZ;
        aggregate_bf16_kernel<<<agrid, 256, 0, stream>>>(hin, ldh, offs, adj, mB);
        sage_mfma_kernel<<<ggrid, 256, 0, stream>>>(
            mB, hin, ldh, WT + (size_t)i * 128 * 256, bl + (size_t)i * D,
            z + (size_t)i * D, DZ);
    }

    mlp1_mfma_kernel<<<ggrid, 256, 0, stream>>>(z, W1T, b1, z1);
    mlp2_lsm_mfma_kernel<<<g16, 256, 0, stream>>>(z1, W2T, b2, out);
}

// Round 8
// 234.976 us; speedup vs baseline: 7.9512x; 1.1721x over previous
//
#include <hip/hip_runtime.h>
#include <math.h>

#define N_NODES 50000
#define D 128
#define LAYERS 3
#define DZ 384
#define DOUT 40
#define BUCKETS 196          // ceil(50000/256)
#define BR 32                // rows per block in fused kernels

typedef __attribute__((ext_vector_type(4))) float f32x4;
typedef __attribute__((ext_vector_type(8))) short short8;

static __device__ __forceinline__ unsigned short f2bf(float f) {
    unsigned int u = __float_as_uint(f);
    u += 0x7FFFu + ((u >> 16) & 1u);
    return (unsigned short)(u >> 16);
}
static __device__ __forceinline__ float bf2f(unsigned short s) {
    return __uint_as_float(((unsigned int)s) << 16);
}

// ---------------- CSR build: atomic-free two-level counting sort ----------------

__global__ __launch_bounds__(256) void hist1_kernel(const int* __restrict__ dst, int E, int CH,
                                                    int nblk1, int* __restrict__ H) {
    __shared__ int h[BUCKETS];
    int t = threadIdx.x;
    if (t < BUCKETS) h[t] = 0;
    __syncthreads();
    int s = blockIdx.x * CH, e = min(E, s + CH);
    for (int i = s + t; i < e; i += 256) atomicAdd(&h[dst[i] >> 8], 1);
    __syncthreads();
    if (t < BUCKETS) H[t * nblk1 + blockIdx.x] = h[t];
}

__global__ __launch_bounds__(512) void scanS_kernel(int* __restrict__ H, int nblk1,
                                                    int* __restrict__ T) {
    __shared__ int s[512];
    int t = threadIdx.x, k = blockIdx.x;
    int v = (t < nblk1) ? H[k * nblk1 + t] : 0;
    s[t] = v;
    __syncthreads();
    for (int off = 1; off < 512; off <<= 1) {
        int u = (t >= off) ? s[t - off] : 0;
        __syncthreads();
        s[t] += u;
        __syncthreads();
    }
    if (t < nblk1) H[k * nblk1 + t] = s[t] - v;
    if (t == 511) T[k] = s[511];
}

__global__ __launch_bounds__(256) void bstart_kernel(const int* __restrict__ T,
                                                     int* __restrict__ bucketStart,
                                                     int* __restrict__ offs, int E) {
    __shared__ int s[256];
    int t = threadIdx.x;
    int v = (t < BUCKETS) ? T[t] : 0;
    s[t] = v;
    __syncthreads();
    for (int off = 1; off < 256; off <<= 1) {
        int u = (t >= off) ? s[t - off] : 0;
        __syncthreads();
        s[t] += u;
        __syncthreads();
    }
    if (t < BUCKETS) bucketStart[t] = s[t] - v;
    if (t == 0) { bucketStart[BUCKETS] = E; offs[N_NODES] = E; }
}

__global__ __launch_bounds__(256) void scatter_kernel(const int* __restrict__ src,
                                                      const int* __restrict__ dst, int E, int CH,
                                                      int nblk1, const int* __restrict__ H,
                                                      const int* __restrict__ bucketStart,
                                                      unsigned int* __restrict__ recs) {
    __shared__ int cur[BUCKETS];
    int t = threadIdx.x;
    if (t < BUCKETS) cur[t] = bucketStart[t] + H[t * nblk1 + blockIdx.x];
    __syncthreads();
    int s = blockIdx.x * CH, e = min(E, s + CH);
    for (int i = s + t; i < e; i += 256) {
        int d = dst[i];
        int pos = atomicAdd(&cur[d >> 8], 1);
        recs[pos] = (unsigned int)(src[i] & 0xFFFF) | ((unsigned int)(d & 255) << 16);
    }
}

__global__ __launch_bounds__(256) void bucket_csr_kernel(const unsigned int* __restrict__ recs,
                                                         const int* __restrict__ bucketStart,
                                                         int* __restrict__ offs,
                                                         unsigned short* __restrict__ adj) {
    __shared__ int h[256];
    __shared__ int sc[256];
    __shared__ int cur[256];
    int t = threadIdx.x, k = blockIdx.x;
    int bs = bucketStart[k], be = bucketStart[k + 1];
    h[t] = 0;
    __syncthreads();
    for (int i = bs + t; i < be; i += 256) atomicAdd(&h[(recs[i] >> 16) & 255], 1);
    __syncthreads();
    int v = h[t];
    sc[t] = v;
    __syncthreads();
    for (int off = 1; off < 256; off <<= 1) {
        int u = (t >= off) ? sc[t - off] : 0;
        __syncthreads();
        sc[t] += u;
        __syncthreads();
    }
    int excl = sc[t] - v;
    int node = k * 256 + t;
    if (node < N_NODES) offs[node] = bs + excl;
    cur[t] = bs + excl;
    __syncthreads();
    for (int i = bs + t; i < be; i += 256) {
        unsigned int r = recs[i];
        int pos = atomicAdd(&cur[(r >> 16) & 255], 1);
        adj[pos] = (unsigned short)(r & 0xFFFF);
    }
}

// ---------------- fused conversions + weight packing ----------------
// range-dispatched: [0,n4) cvt x ; then packWT ; packW1T ; packW2T
__global__ __launch_bounds__(256) void prep_kernel(const float* __restrict__ x,
                                                   const float* __restrict__ Wl,
                                                   const float* __restrict__ Wr,
                                                   const float* __restrict__ W1,
                                                   const float* __restrict__ W2,
                                                   unsigned short* __restrict__ xb,
                                                   unsigned short* __restrict__ WT,
                                                   unsigned short* __restrict__ W1T,
                                                   unsigned short* __restrict__ W2T,
                                                   int n4) {
    int i = blockIdx.x * blockDim.x + threadIdx.x;
    if (i < n4) {
        const float4 v = ((const float4*)x)[i];
        unsigned int lo = ((unsigned int)f2bf(v.y) << 16) | f2bf(v.x);
        unsigned int hi = ((unsigned int)f2bf(v.w) << 16) | f2bf(v.z);
        ((unsigned int*)xb)[i * 2] = lo;
        ((unsigned int*)xb)[i * 2 + 1] = hi;
        return;
    }
    int j = i - n4;
    if (j < LAYERS * 128 * 256) {
        int layer = j >> 15;
        int r = j & 32767;
        int c = r >> 8, k = r & 255;
        const float* W = (k < 128) ? (Wl + layer * 16384) : (Wr + layer * 16384);
        WT[j] = f2bf(W[(k & 127) * 128 + c]);
        return;
    }
    j -= LAYERS * 128 * 256;
    if (j < 128 * 384) {
        int c = j / 384, k = j - c * 384;
        W1T[j] = f2bf(W1[k * 128 + c]);
        return;
    }
    j -= 128 * 384;
    if (j < 48 * 128) {
        int c = j >> 7, k = j & 127;
        W2T[j] = (c < DOUT) ? f2bf(W2[k * DOUT + c]) : (unsigned short)0;
    }
}

// ---------------- fused mean-aggregate + SAGE GEMM ----------------
// block = 256 thr = 4 waves, tile = BR(32) rows.
// Phase 1: each wave gathers means for 8 nodes (4 edge-groups of 16 lanes) -> LDS
// Phase 2: MFMA GEMM, K=256 (m from LDS, h from global), wave owns 32-col stripe
__global__ __launch_bounds__(256) void sage_fused_kernel(
        const unsigned short* __restrict__ h, int ldh,
        const int* __restrict__ offs, const unsigned short* __restrict__ adj,
        const unsigned short* __restrict__ WT,   // [128][256]
        const float* __restrict__ bl,
        unsigned short* __restrict__ zout, int ldz) {
    __shared__ unsigned short mlds[BR][136];   // +8 pad -> 272B stride, ~2-way banks
    int tid = threadIdx.x;
    int wid = tid >> 6;
    int lane = tid & 63;
    int grp = lane >> 4, l16 = lane & 15;
    int r0 = blockIdx.x * BR;

    // ---- phase 1: gather
    for (int i = 0; i < 8; ++i) {
        int nn = wid * 8 + i;
        int node = r0 + nn;
        float acc[8];
#pragma unroll
        for (int j = 0; j < 8; ++j) acc[j] = 0.f;
        int s = 0, e = 0;
        if (node < N_NODES) { s = offs[node]; e = offs[node + 1]; }
        int k = s + grp;
        for (; k + 4 < e; k += 8) {
            int s0 = adj[k], s1 = adj[k + 4];
            short8 v0 = *(const short8*)(h + (size_t)s0 * ldh + l16 * 8);
            short8 v1 = *(const short8*)(h + (size_t)s1 * ldh + l16 * 8);
#pragma unroll
            for (int j = 0; j < 8; ++j)
                acc[j] += bf2f((unsigned short)v0[j]) + bf2f((unsigned short)v1[j]);
        }
        if (k < e) {
            int s0 = adj[k];
            short8 v0 = *(const short8*)(h + (size_t)s0 * ldh + l16 * 8);
#pragma unroll
            for (int j = 0; j < 8; ++j) acc[j] += bf2f((unsigned short)v0[j]);
        }
#pragma unroll
        for (int j = 0; j < 8; ++j) {
            float a = acc[j];
            a += __shfl_xor(a, 16);
            a += __shfl_xor(a, 32);
            acc[j] = a;
        }
        if (grp == 0) {
            float inv = 1.f / fmaxf((float)(e - s), 1.f);
            uint4 o;
            o.x = ((unsigned int)f2bf(acc[1] * inv) << 16) | f2bf(acc[0] * inv);
            o.y = ((unsigned int)f2bf(acc[3] * inv) << 16) | f2bf(acc[2] * inv);
            o.z = ((unsigned int)f2bf(acc[5] * inv) << 16) | f2bf(acc[4] * inv);
            o.w = ((unsigned int)f2bf(acc[7] * inv) << 16) | f2bf(acc[6] * inv);
            *(uint4*)(&mlds[nn][l16 * 8]) = o;
        }
    }
    __syncthreads();

    // ---- phase 2: GEMM. wave cols [wid*32, wid*32+32)
    int lrow = lane & 15;
    int lk8 = (lane >> 4) * 8;
    f32x4 acc0[2], acc1[2];
#pragma unroll
    for (int t = 0; t < 2; ++t) { acc0[t] = (f32x4){0.f,0.f,0.f,0.f}; acc1[t] = (f32x4){0.f,0.f,0.f,0.f}; }

    int rA = r0 + lrow, rB = r0 + 16 + lrow;
    int rAc = (rA < N_NODES) ? rA : (N_NODES - 1);
    int rBc = (rB < N_NODES) ? rB : (N_NODES - 1);
    const unsigned short* aH0 = h + (size_t)rAc * ldh + lk8;
    const unsigned short* aH1 = h + (size_t)rBc * ldh + lk8;
    int colBase = wid * 32;

#pragma unroll
    for (int kc = 0; kc < 8; ++kc) {
        short8 aF0, aF1;
        if (kc < 4) {
            aF0 = *(const short8*)(&mlds[lrow][kc * 32 + lk8]);
            aF1 = *(const short8*)(&mlds[16 + lrow][kc * 32 + lk8]);
        } else {
            aF0 = *(const short8*)(aH0 + (kc - 4) * 32);
            aF1 = *(const short8*)(aH1 + (kc - 4) * 32);
        }
#pragma unroll
        for (int ctl = 0; ctl < 2; ++ctl) {
            short8 bF = *(const short8*)(WT + (size_t)(colBase + ctl * 16 + lrow) * 256 + kc * 32 + lk8);
            acc0[ctl] = __builtin_amdgcn_mfma_f32_16x16x32_bf16(aF0, bF, acc0[ctl], 0, 0, 0);
            acc1[ctl] = __builtin_amdgcn_mfma_f32_16x16x32_bf16(aF1, bF, acc1[ctl], 0, 0, 0);
        }
    }

    int ocol = lane & 15;
    int orow0 = r0 + (lane >> 4) * 4;
#pragma unroll
    for (int ctl = 0; ctl < 2; ++ctl) {
        int col = colBase + ctl * 16 + ocol;
        float b = bl[col];
#pragma unroll
        for (int j = 0; j < 4; ++j) {
            int ra = orow0 + j;
            int rb = ra + 16;
            if (ra < N_NODES) zout[(size_t)ra * ldz + col] = f2bf(acc0[ctl][j] + b);
            if (rb < N_NODES) zout[(size_t)rb * ldz + col] = f2bf(acc1[ctl][j] + b);
        }
    }
}

// ---------------- fused MLP: z1 = relu(z@W1+b1) (LDS) ; out = log_softmax(z1@W2+b2) ----------------
__global__ __launch_bounds__(256) void mlp_fused_kernel(
        const unsigned short* __restrict__ zB,   // [N,384]
        const unsigned short* __restrict__ W1T,  // [128][384]
        const float* __restrict__ b1,
        const unsigned short* __restrict__ W2T,  // [48][128]
        const float* __restrict__ b2,
        float* __restrict__ out) {
    __shared__ unsigned short z1lds[BR][136];
    int tid = threadIdx.x;
    int wid = tid >> 6;
    int lane = tid & 63;
    int r0 = blockIdx.x * BR;
    int lrow = lane & 15;
    int lk8 = (lane >> 4) * 8;

    // ---- phase A: 32 rows x 32 cols per wave, K=384
    f32x4 acc0[2], acc1[2];
#pragma unroll
    for (int t = 0; t < 2; ++t) { acc0[t] = (f32x4){0.f,0.f,0.f,0.f}; acc1[t] = (f32x4){0.f,0.f,0.f,0.f}; }

    int rA = r0 + lrow, rB = r0 + 16 + lrow;
    int rAc = (rA < N_NODES) ? rA : (N_NODES - 1);
    int rBc = (rB < N_NODES) ? rB : (N_NODES - 1);
    const unsigned short* aP0 = zB + (size_t)rAc * DZ + lk8;
    const unsigned short* aP1 = zB + (size_t)rBc * DZ + lk8;
    int colBase = wid * 32;

#pragma unroll
    for (int kc = 0; kc < 12; ++kc) {
        short8 aF0 = *(const short8*)(aP0 + kc * 32);
        short8 aF1 = *(const short8*)(aP1 + kc * 32);
#pragma unroll
        for (int ctl = 0; ctl < 2; ++ctl) {
            short8 bF = *(const short8*)(W1T + (size_t)(colBase + ctl * 16 + lrow) * DZ + kc * 32 + lk8);
            acc0[ctl] = __builtin_amdgcn_mfma_f32_16x16x32_bf16(aF0, bF, acc0[ctl], 0, 0, 0);
            acc1[ctl] = __builtin_amdgcn_mfma_f32_16x16x32_bf16(aF1, bF, acc1[ctl], 0, 0, 0);
        }
    }

    int ocol = lane & 15;
    int lrow0 = (lane >> 4) * 4;
#pragma unroll
    for (int ctl = 0; ctl < 2; ++ctl) {
        int col = colBase + ctl * 16 + ocol;
        float b = b1[col];
#pragma unroll
        for (int j = 0; j < 4; ++j) {
            z1lds[lrow0 + j][col] = f2bf(fmaxf(acc0[ctl][j] + b, 0.f));
            z1lds[16 + lrow0 + j][col] = f2bf(fmaxf(acc1[ctl][j] + b, 0.f));
        }
    }
    __syncthreads();

    // ---- phase B: waves 0,1 -> 16 rows x 48 cols, K=128, + log-softmax
    if (wid < 2) {
        f32x4 acc[3];
#pragma unroll
        for (int t = 0; t < 3; ++t) acc[t] = (f32x4){0.f,0.f,0.f,0.f};
        int lr = wid * 16 + lrow;
#pragma unroll
        for (int kc = 0; kc < 4; ++kc) {
            short8 aF = *(const short8*)(&z1lds[lr][kc * 32 + lk8]);
#pragma unroll
            for (int ct = 0; ct < 3; ++ct) {
                short8 bF = *(const short8*)(W2T + (size_t)(ct * 16 + lrow) * 128 + kc * 32 + lk8);
                acc[ct] = __builtin_amdgcn_mfma_f32_16x16x32_bf16(aF, bF, acc[ct], 0, 0, 0);
            }
        }

        float b0 = b2[ocol];
        float b1v = b2[16 + ocol];
        float b2v = (ocol < 8) ? b2[32 + ocol] : 0.f;

#pragma unroll
        for (int j = 0; j < 4; ++j) {
            int orow = r0 + wid * 16 + (lane >> 4) * 4 + j;
            float v0 = acc[0][j] + b0;
            float v1 = acc[1][j] + b1v;
            float v2 = (ocol < 8) ? (acc[2][j] + b2v) : -1e30f;
            float mx = fmaxf(fmaxf(v0, v1), v2);
            mx = fmaxf(mx, __shfl_xor(mx, 1));
            mx = fmaxf(mx, __shfl_xor(mx, 2));
            mx = fmaxf(mx, __shfl_xor(mx, 4));
            mx = fmaxf(mx, __shfl_xor(mx, 8));
            float es = expf(v0 - mx) + expf(v1 - mx) + ((ocol < 8) ? expf(v2 - mx) : 0.f);
            es += __shfl_xor(es, 1);
            es += __shfl_xor(es, 2);
            es += __shfl_xor(es, 4);
            es += __shfl_xor(es, 8);
            float ls = logf(es);
            if (orow < N_NODES) {
                out[(size_t)orow * DOUT + ocol] = v0 - mx - ls;
                out[(size_t)orow * DOUT + 16 + ocol] = v1 - mx - ls;
                if (ocol < 8) out[(size_t)orow * DOUT + 32 + ocol] = v2 - mx - ls;
            }
        }
    }
}

// ---------------- launch ----------------

extern "C" void kernel_launch(void* const* d_in, const int* in_sizes, int n_in,
                              void* d_out, int out_size, void* d_ws, size_t ws_size,
                              hipStream_t stream) {
    const float* x   = (const float*)d_in[0];
    const int*   ei  = (const int*)d_in[1];
    const float* Wl  = (const float*)d_in[2];
    const float* Wr  = (const float*)d_in[3];
    const float* bl  = (const float*)d_in[4];
    const float* W1  = (const float*)d_in[5];
    const float* b1  = (const float*)d_in[6];
    const float* W2  = (const float*)d_in[7];
    const float* b2  = (const float*)d_in[8];
    float* out = (float*)d_out;

    const int E = in_sizes[1] / 2;
    const int* src = ei;
    const int* dst = ei + E;

    int CH = 2048;
    int nblk1 = (E + CH - 1) / CH;
    if (nblk1 > 512) { CH = ((E + 511) / 512 + 255) & ~255; nblk1 = (E + CH - 1) / CH; }

    char* p = (char*)d_ws;
    auto take = [&p](size_t bytes) { char* q = p; p += (bytes + 255) & ~(size_t)255; return q; };
    int* offs        = (int*)take((N_NODES + 1) * sizeof(int));
    int* H           = (int*)take((size_t)BUCKETS * nblk1 * sizeof(int));
    int* T           = (int*)take(BUCKETS * sizeof(int));
    int* bucketStart = (int*)take((BUCKETS + 1) * sizeof(int));
    unsigned int*   recs = (unsigned int*)take((size_t)E * sizeof(unsigned int));
    unsigned short* adj  = (unsigned short*)take((size_t)E * sizeof(unsigned short));
    unsigned short* xb  = (unsigned short*)take((size_t)N_NODES * D * 2);
    unsigned short* z   = (unsigned short*)take((size_t)N_NODES * DZ * 2);
    unsigned short* WT  = (unsigned short*)take((size_t)LAYERS * 128 * 256 * 2);
    unsigned short* W1T = (unsigned short*)take((size_t)128 * 384 * 2);
    unsigned short* W2T = (unsigned short*)take((size_t)48 * 128 * 2);

    // prep: cvt + all weight packs in one kernel
    int n4 = N_NODES * D / 4;
    int prep_total = n4 + LAYERS * 128 * 256 + 128 * 384 + 48 * 128;
    prep_kernel<<<(prep_total + 255) / 256, 256, 0, stream>>>(
        x, Wl, Wr, W1, W2, xb, WT, W1T, W2T, n4);

    // CSR via counting sort (no global atomics)
    hist1_kernel<<<nblk1, 256, 0, stream>>>(dst, E, CH, nblk1, H);
    scanS_kernel<<<BUCKETS, 512, 0, stream>>>(H, nblk1, T);
    bstart_kernel<<<1, 256, 0, stream>>>(T, bucketStart, offs, E);
    scatter_kernel<<<nblk1, 256, 0, stream>>>(src, dst, E, CH, nblk1, H, bucketStart, recs);
    bucket_csr_kernel<<<BUCKETS, 256, 0, stream>>>(recs, bucketStart, offs, adj);

    int fgrid = (N_NODES + BR - 1) / BR;   // 1563

    for (int i = 0; i < LAYERS; ++i) {
        const unsigned short* hin = (i == 0) ? xb : (z + (size_t)(i - 1) * D);
        int ldh = (i == 0) ? D : DZ;
        sage_fused_kernel<<<fgrid, 256, 0, stream>>>(
            hin, ldh, offs, adj, WT + (size_t)i * 128 * 256, bl + (size_t)i * D,
            z + (size_t)i * D, DZ);
    }

    mlp_fused_kernel<<<fgrid, 256, 0, stream>>>(z, W1T, b1, W2T, b2, out);
}

// Round 11
// 225.865 us; speedup vs baseline: 8.2719x; 1.0403x over previous
//
#include <hip/hip_runtime.h>
#include <math.h>

#define N_NODES 50000
#define D 128
#define LAYERS 3
#define DZ 384
#define DOUT 40
#define BUCKETS 196          // ceil(50000/256)
#define BR 32                // rows per block in fused kernels

typedef __attribute__((ext_vector_type(4))) float f32x4;
typedef __attribute__((ext_vector_type(8))) short short8;

static __device__ __forceinline__ unsigned short f2bf(float f) {
    unsigned int u = __float_as_uint(f);
    u += 0x7FFFu + ((u >> 16) & 1u);
    return (unsigned short)(u >> 16);
}
static __device__ __forceinline__ float bflo(unsigned int u) {
    return __uint_as_float(u << 16);
}
static __device__ __forceinline__ float bfhi(unsigned int u) {
    return __uint_as_float(u & 0xFFFF0000u);
}
static __device__ __forceinline__ void accq(float* acc, uint4 q, float wgt) {
    acc[0] = fmaf(wgt, bflo(q.x), acc[0]);
    acc[1] = fmaf(wgt, bfhi(q.x), acc[1]);
    acc[2] = fmaf(wgt, bflo(q.y), acc[2]);
    acc[3] = fmaf(wgt, bfhi(q.y), acc[3]);
    acc[4] = fmaf(wgt, bflo(q.z), acc[4]);
    acc[5] = fmaf(wgt, bfhi(q.z), acc[5]);
    acc[6] = fmaf(wgt, bflo(q.w), acc[6]);
    acc[7] = fmaf(wgt, bfhi(q.w), acc[7]);
}

// ---------------- CSR build: atomic-free two-level counting sort ----------------

__global__ __launch_bounds__(256) void hist1_kernel(const int* __restrict__ dst, int E, int CH,
                                                    int nblk1, int* __restrict__ H) {
    __shared__ int h[BUCKETS];
    int t = threadIdx.x;
    if (t < BUCKETS) h[t] = 0;
    __syncthreads();
    int s = blockIdx.x * CH, e = min(E, s + CH);
    for (int i = s + t; i < e; i += 256) atomicAdd(&h[dst[i] >> 8], 1);
    __syncthreads();
    if (t < BUCKETS) H[t * nblk1 + blockIdx.x] = h[t];
}

__global__ __launch_bounds__(512) void scanS_kernel(int* __restrict__ H, int nblk1,
                                                    int* __restrict__ T) {
    __shared__ int s[512];
    int t = threadIdx.x, k = blockIdx.x;
    int v = (t < nblk1) ? H[k * nblk1 + t] : 0;
    s[t] = v;
    __syncthreads();
    for (int off = 1; off < 512; off <<= 1) {
        int u = (t >= off) ? s[t - off] : 0;
        __syncthreads();
        s[t] += u;
        __syncthreads();
    }
    if (t < nblk1) H[k * nblk1 + t] = s[t] - v;
    if (t == 511) T[k] = s[511];
}

__global__ __launch_bounds__(256) void bstart_kernel(const int* __restrict__ T,
                                                     int* __restrict__ bucketStart,
                                                     int* __restrict__ offs, int E) {
    __shared__ int s[256];
    int t = threadIdx.x;
    int v = (t < BUCKETS) ? T[t] : 0;
    s[t] = v;
    __syncthreads();
    for (int off = 1; off < 256; off <<= 1) {
        int u = (t >= off) ? s[t - off] : 0;
        __syncthreads();
        s[t] += u;
        __syncthreads();
    }
    if (t < BUCKETS) bucketStart[t] = s[t] - v;
    if (t == 0) { bucketStart[BUCKETS] = E; offs[N_NODES] = E; }
}

__global__ __launch_bounds__(256) void scatter_kernel(const int* __restrict__ src,
                                                      const int* __restrict__ dst, int E, int CH,
                                                      int nblk1, const int* __restrict__ H,
                                                      const int* __restrict__ bucketStart,
                                                      unsigned int* __restrict__ recs) {
    __shared__ int cur[BUCKETS];
    int t = threadIdx.x;
    if (t < BUCKETS) cur[t] = bucketStart[t] + H[t * nblk1 + blockIdx.x];
    __syncthreads();
    int s = blockIdx.x * CH, e = min(E, s + CH);
    for (int i = s + t; i < e; i += 256) {
        int d = dst[i];
        int pos = atomicAdd(&cur[d >> 8], 1);
        recs[pos] = (unsigned int)(src[i] & 0xFFFF) | ((unsigned int)(d & 255) << 16);
    }
}

__global__ __launch_bounds__(256) void bucket_csr_kernel(const unsigned int* __restrict__ recs,
                                                         const int* __restrict__ bucketStart,
                                                         int* __restrict__ offs,
                                                         unsigned short* __restrict__ adj) {
    __shared__ int h[256];
    __shared__ int sc[256];
    __shared__ int cur[256];
    int t = threadIdx.x, k = blockIdx.x;
    int bs = bucketStart[k], be = bucketStart[k + 1];
    h[t] = 0;
    __syncthreads();
    for (int i = bs + t; i < be; i += 256) atomicAdd(&h[(recs[i] >> 16) & 255], 1);
    __syncthreads();
    int v = h[t];
    sc[t] = v;
    __syncthreads();
    for (int off = 1; off < 256; off <<= 1) {
        int u = (t >= off) ? sc[t - off] : 0;
        __syncthreads();
        sc[t] += u;
        __syncthreads();
    }
    int excl = sc[t] - v;
    int node = k * 256 + t;
    if (node < N_NODES) offs[node] = bs + excl;
    cur[t] = bs + excl;
    __syncthreads();
    for (int i = bs + t; i < be; i += 256) {
        unsigned int r = recs[i];
        int pos = atomicAdd(&cur[(r >> 16) & 255], 1);
        adj[pos] = (unsigned short)(r & 0xFFFF);
    }
}

// ---------------- fused conversions + weight packing ----------------

__global__ __launch_bounds__(256) void prep_kernel(const float* __restrict__ x,
                                                   const float* __restrict__ Wl,
                                                   const float* __restrict__ Wr,
                                                   const float* __restrict__ W1,
                                                   const float* __restrict__ W2,
                                                   unsigned short* __restrict__ xb,
                                                   unsigned short* __restrict__ WT,
                                                   unsigned short* __restrict__ W1T,
                                                   unsigned short* __restrict__ W2T,
                                                   int n4) {
    int i = blockIdx.x * blockDim.x + threadIdx.x;
    if (i < n4) {
        const float4 v = ((const float4*)x)[i];
        unsigned int lo = ((unsigned int)f2bf(v.y) << 16) | f2bf(v.x);
        unsigned int hi = ((unsigned int)f2bf(v.w) << 16) | f2bf(v.z);
        ((unsigned int*)xb)[i * 2] = lo;
        ((unsigned int*)xb)[i * 2 + 1] = hi;
        return;
    }
    int j = i - n4;
    if (j < LAYERS * 128 * 256) {
        int layer = j >> 15;
        int r = j & 32767;
        int c = r >> 8, k = r & 255;
        const float* W = (k < 128) ? (Wl + layer * 16384) : (Wr + layer * 16384);
        WT[j] = f2bf(W[(k & 127) * 128 + c]);
        return;
    }
    j -= LAYERS * 128 * 256;
    if (j < 128 * 384) {
        int c = j / 384, k = j - c * 384;
        W1T[j] = f2bf(W1[k * 128 + c]);
        return;
    }
    j -= 128 * 384;
    if (j < 48 * 128) {
        int c = j >> 7, k = j & 127;
        W2T[j] = (c < DOUT) ? f2bf(W2[k * DOUT + c]) : (unsigned short)0;
    }
}

// ---------------- fused mean-aggregate + SAGE GEMM ----------------
// block = 256 thr = 4 waves, tile = BR(32) rows.
// Phase 1: 16 groups of 16 lanes; group owns 2 nodes, serial edge walk,
//          4-deep unrolled clamped loads + select-weighted fma accumulate.
// Phase 2: MFMA GEMM, K=256 (m from LDS, h from global), wave owns 32-col stripe.
__global__ __launch_bounds__(256) void sage_fused_kernel(
        const unsigned short* __restrict__ h,    // [N,128] prev-layer features
        const int* __restrict__ offs, const unsigned short* __restrict__ adj,
        const unsigned short* __restrict__ WT,   // [128][256]
        const float* __restrict__ bl,
        unsigned short* __restrict__ zout) {     // [N,128]
    __shared__ unsigned short mlds[BR][136];   // 272B row stride, 16B aligned
    int tid = threadIdx.x;
    int r0 = blockIdx.x * BR;
    int gid = tid >> 4, l16 = tid & 15;

    // ---- phase 1: gather (group gid -> nodes r0+gid*2, +1)
    const unsigned short* hb = h + l16 * 8;
#pragma unroll
    for (int t = 0; t < 2; ++t) {
        int nn = gid * 2 + t;
        int node = r0 + nn;
        float acc[8];
#pragma unroll
        for (int j = 0; j < 8; ++j) acc[j] = 0.f;
        int s = 0, e = 0;
        if (node < N_NODES) { s = offs[node]; e = offs[node + 1]; }
        for (int k = s; k < e; k += 4) {
            int e1 = e - 1;
            int a0 = adj[k];
            int a1 = adj[min(k + 1, e1)];
            int a2 = adj[min(k + 2, e1)];
            int a3 = adj[min(k + 3, e1)];
            uint4 q0 = *(const uint4*)(hb + (size_t)a0 * D);
            uint4 q1 = *(const uint4*)(hb + (size_t)a1 * D);
            uint4 q2 = *(const uint4*)(hb + (size_t)a2 * D);
            uint4 q3 = *(const uint4*)(hb + (size_t)a3 * D);
            float w1 = (k + 1 < e) ? 1.f : 0.f;
            float w2 = (k + 2 < e) ? 1.f : 0.f;
            float w3 = (k + 3 < e) ? 1.f : 0.f;
            accq(acc, q0, 1.f);
            accq(acc, q1, w1);
            accq(acc, q2, w2);
            accq(acc, q3, w3);
        }
        float inv = 1.f / fmaxf((float)(e - s), 1.f);
        uint4 o;
        o.x = ((unsigned int)f2bf(acc[1] * inv) << 16) | f2bf(acc[0] * inv);
        o.y = ((unsigned int)f2bf(acc[3] * inv) << 16) | f2bf(acc[2] * inv);
        o.z = ((unsigned int)f2bf(acc[5] * inv) << 16) | f2bf(acc[4] * inv);
        o.w = ((unsigned int)f2bf(acc[7] * inv) << 16) | f2bf(acc[6] * inv);
        *(uint4*)(&mlds[nn][l16 * 8]) = o;
    }
    __syncthreads();

    // ---- phase 2: GEMM. wave cols [wid*32, wid*32+32)
    int wid = tid >> 6;
    int lane = tid & 63;
    int lrow = lane & 15;
    int lk8 = (lane >> 4) * 8;
    f32x4 acc0[2], acc1[2];
#pragma unroll
    for (int t = 0; t < 2; ++t) { acc0[t] = (f32x4){0.f,0.f,0.f,0.f}; acc1[t] = (f32x4){0.f,0.f,0.f,0.f}; }

    int rA = r0 + lrow, rB = r0 + 16 + lrow;
    int rAc = (rA < N_NODES) ? rA : (N_NODES - 1);
    int rBc = (rB < N_NODES) ? rB : (N_NODES - 1);
    const unsigned short* aH0 = h + (size_t)rAc * D + lk8;
    const unsigned short* aH1 = h + (size_t)rBc * D + lk8;
    int colBase = wid * 32;

#pragma unroll
    for (int kc = 0; kc < 8; ++kc) {
        short8 aF0, aF1;
        if (kc < 4) {
            aF0 = *(const short8*)(&mlds[lrow][kc * 32 + lk8]);
            aF1 = *(const short8*)(&mlds[16 + lrow][kc * 32 + lk8]);
        } else {
            aF0 = *(const short8*)(aH0 + (kc - 4) * 32);
            aF1 = *(const short8*)(aH1 + (kc - 4) * 32);
        }
#pragma unroll
        for (int ctl = 0; ctl < 2; ++ctl) {
            short8 bF = *(const short8*)(WT + (size_t)(colBase + ctl * 16 + lrow) * 256 + kc * 32 + lk8);
            acc0[ctl] = __builtin_amdgcn_mfma_f32_16x16x32_bf16(aF0, bF, acc0[ctl], 0, 0, 0);
            acc1[ctl] = __builtin_amdgcn_mfma_f32_16x16x32_bf16(aF1, bF, acc1[ctl], 0, 0, 0);
        }
    }

    int ocol = lane & 15;
    int orow0 = r0 + (lane >> 4) * 4;
#pragma unroll
    for (int ctl = 0; ctl < 2; ++ctl) {
        int col = colBase + ctl * 16 + ocol;
        float b = bl[col];
#pragma unroll
        for (int j = 0; j < 4; ++j) {
            int ra = orow0 + j;
            int rb = ra + 16;
            if (ra < N_NODES) zout[(size_t)ra * D + col] = f2bf(acc0[ctl][j] + b);
            if (rb < N_NODES) zout[(size_t)rb * D + col] = f2bf(acc1[ctl][j] + b);
        }
    }
}

// ---------------- fused MLP: z1 = relu([z0|z1|z2]@W1+b1) (LDS) ; out = log_softmax(z1@W2+b2) ----------------
__global__ __launch_bounds__(256) void mlp_fused_kernel(
        const unsigned short* __restrict__ z0,   // [N,128]
        const unsigned short* __restrict__ z1b,  // [N,128]
        const unsigned short* __restrict__ z2,   // [N,128]
        const unsigned short* __restrict__ W1T,  // [128][384]
        const float* __restrict__ b1,
        const unsigned short* __restrict__ W2T,  // [48][128]
        const float* __restrict__ b2,
        float* __restrict__ out) {
    __shared__ unsigned short z1lds[BR][136];
    int tid = threadIdx.x;
    int wid = tid >> 6;
    int lane = tid & 63;
    int r0 = blockIdx.x * BR;
    int lrow = lane & 15;
    int lk8 = (lane >> 4) * 8;

    f32x4 acc0[2], acc1[2];
#pragma unroll
    for (int t = 0; t < 2; ++t) { acc0[t] = (f32x4){0.f,0.f,0.f,0.f}; acc1[t] = (f32x4){0.f,0.f,0.f,0.f}; }

    int rA = r0 + lrow, rB = r0 + 16 + lrow;
    int rAc = (rA < N_NODES) ? rA : (N_NODES - 1);
    int rBc = (rB < N_NODES) ? rB : (N_NODES - 1);
    const unsigned short* zb[3] = {z0, z1b, z2};
    int colBase = wid * 32;

#pragma unroll
    for (int kc = 0; kc < 12; ++kc) {
        const unsigned short* base = zb[kc >> 2];
        short8 aF0 = *(const short8*)(base + (size_t)rAc * D + (kc & 3) * 32 + lk8);
        short8 aF1 = *(const short8*)(base + (size_t)rBc * D + (kc & 3) * 32 + lk8);
#pragma unroll
        for (int ctl = 0; ctl < 2; ++ctl) {
            short8 bF = *(const short8*)(W1T + (size_t)(colBase + ctl * 16 + lrow) * DZ + kc * 32 + lk8);
            acc0[ctl] = __builtin_amdgcn_mfma_f32_16x16x32_bf16(aF0, bF, acc0[ctl], 0, 0, 0);
            acc1[ctl] = __builtin_amdgcn_mfma_f32_16x16x32_bf16(aF1, bF, acc1[ctl], 0, 0, 0);
        }
    }

    int ocol = lane & 15;
    int lrow0 = (lane >> 4) * 4;
#pragma unroll
    for (int ctl = 0; ctl < 2; ++ctl) {
        int col = colBase + ctl * 16 + ocol;
        float b = b1[col];
#pragma unroll
        for (int j = 0; j < 4; ++j) {
            z1lds[lrow0 + j][col] = f2bf(fmaxf(acc0[ctl][j] + b, 0.f));
            z1lds[16 + lrow0 + j][col] = f2bf(fmaxf(acc1[ctl][j] + b, 0.f));
        }
    }
    __syncthreads();

    if (wid < 2) {
        f32x4 acc[3];
#pragma unroll
        for (int t = 0; t < 3; ++t) acc[t] = (f32x4){0.f,0.f,0.f,0.f};
        int lr = wid * 16 + lrow;
#pragma unroll
        for (int kc = 0; kc < 4; ++kc) {
            short8 aF = *(const short8*)(&z1lds[lr][kc * 32 + lk8]);
#pragma unroll
            for (int ct = 0; ct < 3; ++ct) {
                short8 bF = *(const short8*)(W2T + (size_t)(ct * 16 + lrow) * 128 + kc * 32 + lk8);
                acc[ct] = __builtin_amdgcn_mfma_f32_16x16x32_bf16(aF, bF, acc[ct], 0, 0, 0);
            }
        }

        float b0 = b2[ocol];
        float b1v = b2[16 + ocol];
        float b2v = (ocol < 8) ? b2[32 + ocol] : 0.f;

#pragma unroll
        for (int j = 0; j < 4; ++j) {
            int orow = r0 + wid * 16 + (lane >> 4) * 4 + j;
            float v0 = acc[0][j] + b0;
            float v1 = acc[1][j] + b1v;
            float v2 = (ocol < 8) ? (acc[2][j] + b2v) : -1e30f;
            float mx = fmaxf(fmaxf(v0, v1), v2);
            mx = fmaxf(mx, __shfl_xor(mx, 1));
            mx = fmaxf(mx, __shfl_xor(mx, 2));
            mx = fmaxf(mx, __shfl_xor(mx, 4));
            mx = fmaxf(mx, __shfl_xor(mx, 8));
            float es = expf(v0 - mx) + expf(v1 - mx) + ((ocol < 8) ? expf(v2 - mx) : 0.f);
            es += __shfl_xor(es, 1);
            es += __shfl_xor(es, 2);
            es += __shfl_xor(es, 4);
            es += __shfl_xor(es, 8);
            float ls = logf(es);
            if (orow < N_NODES) {
                out[(size_t)orow * DOUT + ocol] = v0 - mx - ls;
                out[(size_t)orow * DOUT + 16 + ocol] = v1 - mx - ls;
                if (ocol < 8) out[(size_t)orow * DOUT + 32 + ocol] = v2 - mx - ls;
            }
        }
    }
}

// ---------------- launch ----------------

extern "C" void kernel_launch(void* const* d_in, const int* in_sizes, int n_in,
                              void* d_out, int out_size, void* d_ws, size_t ws_size,
                              hipStream_t stream) {
    const float* x   = (const float*)d_in[0];
    const int*   ei  = (const int*)d_in[1];
    const float* Wl  = (const float*)d_in[2];
    const float* Wr  = (const float*)d_in[3];
    const float* bl  = (const float*)d_in[4];
    const float* W1  = (const float*)d_in[5];
    const float* b1  = (const float*)d_in[6];
    const float* W2  = (const float*)d_in[7];
    const float* b2  = (const float*)d_in[8];
    float* out = (float*)d_out;

    const int E = in_sizes[1] / 2;
    const int* src = ei;
    const int* dst = ei + E;

    int CH = 2048;
    int nblk1 = (E + CH - 1) / CH;
    if (nblk1 > 512) { CH = ((E + 511) / 512 + 255) & ~255; nblk1 = (E + CH - 1) / CH; }

    char* p = (char*)d_ws;
    auto take = [&p](size_t bytes) { char* q = p; p += (bytes + 255) & ~(size_t)255; return q; };
    int* offs        = (int*)take((N_NODES + 1) * sizeof(int));
    int* H           = (int*)take((size_t)BUCKETS * nblk1 * sizeof(int));
    int* T           = (int*)take(BUCKETS * sizeof(int));
    int* bucketStart = (int*)take((BUCKETS + 1) * sizeof(int));
    unsigned int*   recs = (unsigned int*)take((size_t)E * sizeof(unsigned int));
    unsigned short* adj  = (unsigned short*)take((size_t)E * sizeof(unsigned short));
    unsigned short* xb  = (unsigned short*)take((size_t)N_NODES * D * 2);
    unsigned short* z0  = (unsigned short*)take((size_t)N_NODES * D * 2);
    unsigned short* z1  = (unsigned short*)take((size_t)N_NODES * D * 2);
    unsigned short* z2  = (unsigned short*)take((size_t)N_NODES * D * 2);
    unsigned short* WT  = (unsigned short*)take((size_t)LAYERS * 128 * 256 * 2);
    unsigned short* W1T = (unsigned short*)take((size_t)128 * 384 * 2);
    unsigned short* W2T = (unsigned short*)take((size_t)48 * 128 * 2);

    // prep: cvt + all weight packs in one kernel
    int n4 = N_NODES * D / 4;
    int prep_total = n4 + LAYERS * 128 * 256 + 128 * 384 + 48 * 128;
    prep_kernel<<<(prep_total + 255) / 256, 256, 0, stream>>>(
        x, Wl, Wr, W1, W2, xb, WT, W1T, W2T, n4);

    // CSR via counting sort (no global atomics)
    hist1_kernel<<<nblk1, 256, 0, stream>>>(dst, E, CH, nblk1, H);
    scanS_kernel<<<BUCKETS, 512, 0, stream>>>(H, nblk1, T);
    bstart_kernel<<<1, 256, 0, stream>>>(T, bucketStart, offs, E);
    scatter_kernel<<<nblk1, 256, 0, stream>>>(src, dst, E, CH, nblk1, H, bucketStart, recs);
    bucket_csr_kernel<<<BUCKETS, 256, 0, stream>>>(recs, bucketStart, offs, adj);

    int fgrid = (N_NODES + BR - 1) / BR;   // 1563

    unsigned short* zs[3] = {z0, z1, z2};
    for (int i = 0; i < LAYERS; ++i) {
        const unsigned short* hin = (i == 0) ? xb : zs[i - 1];
        sage_fused_kernel<<<fgrid, 256, 0, stream>>>(
            hin, offs, adj, WT + (size_t)i * 128 * 256, bl + (size_t)i * D, zs[i]);
    }

    mlp_fused_kernel<<<fgrid, 256, 0, stream>>>(z0, z1, z2, W1T, b1, W2T, b2, out);
}

// Round 12
// 198.404 us; speedup vs baseline: 9.4168x; 1.1384x over previous
//
#include <hip/hip_runtime.h>
#include <math.h>

#define N_NODES 50000
#define D 128
#define LAYERS 3
#define DZ 384
#define DOUT 40
#define BUCKETS 196          // ceil(50000/256)
#define BR 32                // rows per block in fused kernels

typedef __attribute__((ext_vector_type(4))) float f32x4;
typedef __attribute__((ext_vector_type(8))) short short8;

static __device__ __forceinline__ unsigned short f2bf(float f) {
    unsigned int u = __float_as_uint(f);
    u += 0x7FFFu + ((u >> 16) & 1u);
    return (unsigned short)(u >> 16);
}
static __device__ __forceinline__ float bflo(unsigned int u) {
    return __uint_as_float(u << 16);
}
static __device__ __forceinline__ float bfhi(unsigned int u) {
    return __uint_as_float(u & 0xFFFF0000u);
}
static __device__ __forceinline__ void accq(float* acc, uint4 q, float wgt) {
    acc[0] = fmaf(wgt, bflo(q.x), acc[0]);
    acc[1] = fmaf(wgt, bfhi(q.x), acc[1]);
    acc[2] = fmaf(wgt, bflo(q.y), acc[2]);
    acc[3] = fmaf(wgt, bfhi(q.y), acc[3]);
    acc[4] = fmaf(wgt, bflo(q.z), acc[4]);
    acc[5] = fmaf(wgt, bfhi(q.z), acc[5]);
    acc[6] = fmaf(wgt, bflo(q.w), acc[6]);
    acc[7] = fmaf(wgt, bfhi(q.w), acc[7]);
}

// ---------------- CSR build: atomic-free two-level counting sort ----------------

__global__ __launch_bounds__(256) void hist1_kernel(const int* __restrict__ dst, int E, int CH,
                                                    int nblk1, int* __restrict__ H) {
    __shared__ int h[BUCKETS];
    int t = threadIdx.x;
    if (t < BUCKETS) h[t] = 0;
    __syncthreads();
    int s = blockIdx.x * CH, e = min(E, s + CH);
    for (int i = s + t; i < e; i += 256) atomicAdd(&h[dst[i] >> 8], 1);
    __syncthreads();
    if (t < BUCKETS) H[t * nblk1 + blockIdx.x] = h[t];
}

__global__ __launch_bounds__(512) void scanS_kernel(int* __restrict__ H, int nblk1,
                                                    int* __restrict__ T) {
    __shared__ int s[512];
    int t = threadIdx.x, k = blockIdx.x;
    int v = (t < nblk1) ? H[k * nblk1 + t] : 0;
    s[t] = v;
    __syncthreads();
    for (int off = 1; off < 512; off <<= 1) {
        int u = (t >= off) ? s[t - off] : 0;
        __syncthreads();
        s[t] += u;
        __syncthreads();
    }
    if (t < nblk1) H[k * nblk1 + t] = s[t] - v;
    if (t == 511) T[k] = s[511];
}

__global__ __launch_bounds__(256) void bstart_kernel(const int* __restrict__ T,
                                                     int* __restrict__ bucketStart,
                                                     int* __restrict__ offs, int E) {
    __shared__ int s[256];
    int t = threadIdx.x;
    int v = (t < BUCKETS) ? T[t] : 0;
    s[t] = v;
    __syncthreads();
    for (int off = 1; off < 256; off <<= 1) {
        int u = (t >= off) ? s[t - off] : 0;
        __syncthreads();
        s[t] += u;
        __syncthreads();
    }
    if (t < BUCKETS) bucketStart[t] = s[t] - v;
    if (t == 0) { bucketStart[BUCKETS] = E; offs[N_NODES] = E; }
}

__global__ __launch_bounds__(256) void scatter_kernel(const int* __restrict__ src,
                                                      const int* __restrict__ dst, int E, int CH,
                                                      int nblk1, const int* __restrict__ H,
                                                      const int* __restrict__ bucketStart,
                                                      unsigned int* __restrict__ recs) {
    __shared__ int cur[BUCKETS];
    int t = threadIdx.x;
    if (t < BUCKETS) cur[t] = bucketStart[t] + H[t * nblk1 + blockIdx.x];
    __syncthreads();
    int s = blockIdx.x * CH, e = min(E, s + CH);
    for (int i = s + t; i < e; i += 256) {
        int d = dst[i];
        int pos = atomicAdd(&cur[d >> 8], 1);
        recs[pos] = (unsigned int)(src[i] & 0xFFFF) | ((unsigned int)(d & 255) << 16);
    }
}

__global__ __launch_bounds__(256) void bucket_csr_kernel(const unsigned int* __restrict__ recs,
                                                         const int* __restrict__ bucketStart,
                                                         int* __restrict__ offs,
                                                         unsigned short* __restrict__ adj) {
    __shared__ int h[256];
    __shared__ int sc[256];
    __shared__ int cur[256];
    int t = threadIdx.x, k = blockIdx.x;
    int bs = bucketStart[k], be = bucketStart[k + 1];
    h[t] = 0;
    __syncthreads();
    for (int i = bs + t; i < be; i += 256) atomicAdd(&h[(recs[i] >> 16) & 255], 1);
    __syncthreads();
    int v = h[t];
    sc[t] = v;
    __syncthreads();
    for (int off = 1; off < 256; off <<= 1) {
        int u = (t >= off) ? sc[t - off] : 0;
        __syncthreads();
        sc[t] += u;
        __syncthreads();
    }
    int excl = sc[t] - v;
    int node = k * 256 + t;
    if (node < N_NODES) offs[node] = bs + excl;
    cur[t] = bs + excl;
    __syncthreads();
    for (int i = bs + t; i < be; i += 256) {
        unsigned int r = recs[i];
        int pos = atomicAdd(&cur[(r >> 16) & 255], 1);
        adj[pos] = (unsigned short)(r & 0xFFFF);
    }
}

// ---------------- fused conversions + weight packing ----------------

__global__ __launch_bounds__(256) void prep_kernel(const float* __restrict__ x,
                                                   const float* __restrict__ Wl,
                                                   const float* __restrict__ Wr,
                                                   const float* __restrict__ W1,
                                                   const float* __restrict__ W2,
                                                   unsigned short* __restrict__ xb,
                                                   unsigned short* __restrict__ WT,
                                                   unsigned short* __restrict__ W1T,
                                                   unsigned short* __restrict__ W2T,
                                                   int n4) {
    int i = blockIdx.x * blockDim.x + threadIdx.x;
    if (i < n4) {
        const float4 v = ((const float4*)x)[i];
        unsigned int lo = ((unsigned int)f2bf(v.y) << 16) | f2bf(v.x);
        unsigned int hi = ((unsigned int)f2bf(v.w) << 16) | f2bf(v.z);
        ((unsigned int*)xb)[i * 2] = lo;
        ((unsigned int*)xb)[i * 2 + 1] = hi;
        return;
    }
    int j = i - n4;
    if (j < LAYERS * 128 * 256) {
        int layer = j >> 15;
        int r = j & 32767;
        int c = r >> 8, k = r & 255;
        const float* W = (k < 128) ? (Wl + layer * 16384) : (Wr + layer * 16384);
        WT[j] = f2bf(W[(k & 127) * 128 + c]);
        return;
    }
    j -= LAYERS * 128 * 256;
    if (j < 128 * 384) {
        int c = j / 384, k = j - c * 384;
        W1T[j] = f2bf(W1[k * 128 + c]);
        return;
    }
    j -= 128 * 384;
    if (j < 48 * 128) {
        int c = j >> 7, k = j & 127;
        W2T[j] = (c < DOUT) ? f2bf(W2[k * DOUT + c]) : (unsigned short)0;
    }
}

// ---------------- fused mean-aggregate + SAGE GEMM ----------------
// Phase 0: cooperative LDS staging of the block's own 32 h-rows (coalesced).
// Phase 1: 16 groups of 16 lanes; group owns 2 nodes, serial edge walk,
//          4-deep unrolled clamped loads + select-weighted fma accumulate.
// Phase 2: MFMA GEMM, K=256; A entirely from LDS (m + own-h), B (WT) from L2.
__global__ __launch_bounds__(256) void sage_fused_kernel(
        const unsigned short* __restrict__ h,    // [N,128] prev-layer features
        const int* __restrict__ offs, const unsigned short* __restrict__ adj,
        const unsigned short* __restrict__ WT,   // [128][256]
        const float* __restrict__ bl,
        unsigned short* __restrict__ zout) {     // [N,128]
    __shared__ unsigned short mlds[BR][136];   // 272B stride: 2-way banks (free)
    __shared__ unsigned short hlds[BR][136];
    int tid = threadIdx.x;
    int r0 = blockIdx.x * BR;
    int gid = tid >> 4, l16 = tid & 15;

    // ---- phase 0: stage own rows (512 chunks of 16B; 2/thread, coalesced)
#pragma unroll
    for (int i = 0; i < 2; ++i) {
        int chunk = tid + i * 256;
        int row = chunk >> 4, c8 = (chunk & 15) * 8;
        int rc = min(r0 + row, N_NODES - 1);
        uint4 q = *(const uint4*)(h + (size_t)rc * D + c8);
        *(uint4*)(&hlds[row][c8]) = q;
    }

    // ---- phase 1: gather (group gid -> nodes r0+gid*2, +1)
    const unsigned short* hb = h + l16 * 8;
#pragma unroll
    for (int t = 0; t < 2; ++t) {
        int nn = gid * 2 + t;
        int node = r0 + nn;
        float acc[8];
#pragma unroll
        for (int j = 0; j < 8; ++j) acc[j] = 0.f;
        int s = 0, e = 0;
        if (node < N_NODES) { s = offs[node]; e = offs[node + 1]; }
        for (int k = s; k < e; k += 4) {
            int e1 = e - 1;
            int a0 = adj[k];
            int a1 = adj[min(k + 1, e1)];
            int a2 = adj[min(k + 2, e1)];
            int a3 = adj[min(k + 3, e1)];
            uint4 q0 = *(const uint4*)(hb + (size_t)a0 * D);
            uint4 q1 = *(const uint4*)(hb + (size_t)a1 * D);
            uint4 q2 = *(const uint4*)(hb + (size_t)a2 * D);
            uint4 q3 = *(const uint4*)(hb + (size_t)a3 * D);
            float w1 = (k + 1 < e) ? 1.f : 0.f;
            float w2 = (k + 2 < e) ? 1.f : 0.f;
            float w3 = (k + 3 < e) ? 1.f : 0.f;
            accq(acc, q0, 1.f);
            accq(acc, q1, w1);
            accq(acc, q2, w2);
            accq(acc, q3, w3);
        }
        float inv = 1.f / fmaxf((float)(e - s), 1.f);
        uint4 o;
        o.x = ((unsigned int)f2bf(acc[1] * inv) << 16) | f2bf(acc[0] * inv);
        o.y = ((unsigned int)f2bf(acc[3] * inv) << 16) | f2bf(acc[2] * inv);
        o.z = ((unsigned int)f2bf(acc[5] * inv) << 16) | f2bf(acc[4] * inv);
        o.w = ((unsigned int)f2bf(acc[7] * inv) << 16) | f2bf(acc[6] * inv);
        *(uint4*)(&mlds[nn][l16 * 8]) = o;
    }
    __syncthreads();

    // ---- phase 2: GEMM. wave cols [wid*32, wid*32+32)
    int wid = tid >> 6;
    int lane = tid & 63;
    int lrow = lane & 15;
    int lk8 = (lane >> 4) * 8;
    f32x4 acc0[2], acc1[2];
#pragma unroll
    for (int t = 0; t < 2; ++t) { acc0[t] = (f32x4){0.f,0.f,0.f,0.f}; acc1[t] = (f32x4){0.f,0.f,0.f,0.f}; }

    int colBase = wid * 32;

#pragma unroll
    for (int kc = 0; kc < 8; ++kc) {
        short8 aF0, aF1;
        if (kc < 4) {
            aF0 = *(const short8*)(&mlds[lrow][kc * 32 + lk8]);
            aF1 = *(const short8*)(&mlds[16 + lrow][kc * 32 + lk8]);
        } else {
            aF0 = *(const short8*)(&hlds[lrow][(kc - 4) * 32 + lk8]);
            aF1 = *(const short8*)(&hlds[16 + lrow][(kc - 4) * 32 + lk8]);
        }
#pragma unroll
        for (int ctl = 0; ctl < 2; ++ctl) {
            short8 bF = *(const short8*)(WT + (size_t)(colBase + ctl * 16 + lrow) * 256 + kc * 32 + lk8);
            acc0[ctl] = __builtin_amdgcn_mfma_f32_16x16x32_bf16(aF0, bF, acc0[ctl], 0, 0, 0);
            acc1[ctl] = __builtin_amdgcn_mfma_f32_16x16x32_bf16(aF1, bF, acc1[ctl], 0, 0, 0);
        }
    }

    int ocol = lane & 15;
    int orow0 = r0 + (lane >> 4) * 4;
#pragma unroll
    for (int ctl = 0; ctl < 2; ++ctl) {
        int col = colBase + ctl * 16 + ocol;
        float b = bl[col];
#pragma unroll
        for (int j = 0; j < 4; ++j) {
            int ra = orow0 + j;
            int rb = ra + 16;
            if (ra < N_NODES) zout[(size_t)ra * D + col] = f2bf(acc0[ctl][j] + b);
            if (rb < N_NODES) zout[(size_t)rb * D + col] = f2bf(acc1[ctl][j] + b);
        }
    }
}

// ---------------- fused MLP: z1 = relu([z0|z1|z2]@W1+b1) ; out = log_softmax(z1@W2+b2) ----------------
// Phase 0: cooperative LDS staging of 32 rows x 384 (z0|z1|z2 concatenated).
__global__ __launch_bounds__(256) void mlp_fused_kernel(
        const unsigned short* __restrict__ z0,   // [N,128]
        const unsigned short* __restrict__ z1b,  // [N,128]
        const unsigned short* __restrict__ z2,   // [N,128]
        const unsigned short* __restrict__ W1T,  // [128][384]
        const float* __restrict__ b1,
        const unsigned short* __restrict__ W2T,  // [48][128]
        const float* __restrict__ b2,
        float* __restrict__ out) {
    __shared__ unsigned short zs[BR][392];   // 784B stride (16B aligned, 2-way banks)
    __shared__ unsigned short z1lds[BR][136];
    int tid = threadIdx.x;
    int wid = tid >> 6;
    int lane = tid & 63;
    int r0 = blockIdx.x * BR;
    int lrow = lane & 15;
    int lk8 = (lane >> 4) * 8;

    // ---- phase 0: stage 3 x (512 chunks of 16B), 6 loads/thread, coalesced
    const unsigned short* zbuf[3] = {z0, z1b, z2};
#pragma unroll
    for (int b = 0; b < 3; ++b) {
#pragma unroll
        for (int i = 0; i < 2; ++i) {
            int chunk = tid + i * 256;
            int row = chunk >> 4, c8 = (chunk & 15) * 8;
            int rc = min(r0 + row, N_NODES - 1);
            uint4 q = *(const uint4*)(zbuf[b] + (size_t)rc * D + c8);
            *(uint4*)(&zs[row][b * 128 + c8]) = q;
        }
    }
    __syncthreads();

    // ---- phase A: 32 rows x 32 cols per wave, K=384, A from LDS
    f32x4 acc0[2], acc1[2];
#pragma unroll
    for (int t = 0; t < 2; ++t) { acc0[t] = (f32x4){0.f,0.f,0.f,0.f}; acc1[t] = (f32x4){0.f,0.f,0.f,0.f}; }

    int colBase = wid * 32;

#pragma unroll
    for (int kc = 0; kc < 12; ++kc) {
        short8 aF0 = *(const short8*)(&zs[lrow][kc * 32 + lk8]);
        short8 aF1 = *(const short8*)(&zs[16 + lrow][kc * 32 + lk8]);
#pragma unroll
        for (int ctl = 0; ctl < 2; ++ctl) {
            short8 bF = *(const short8*)(W1T + (size_t)(colBase + ctl * 16 + lrow) * DZ + kc * 32 + lk8);
            acc0[ctl] = __builtin_amdgcn_mfma_f32_16x16x32_bf16(aF0, bF, acc0[ctl], 0, 0, 0);
            acc1[ctl] = __builtin_amdgcn_mfma_f32_16x16x32_bf16(aF1, bF, acc1[ctl], 0, 0, 0);
        }
    }

    int ocol = lane & 15;
    int lrow0 = (lane >> 4) * 4;
#pragma unroll
    for (int ctl = 0; ctl < 2; ++ctl) {
        int col = colBase + ctl * 16 + ocol;
        float b = b1[col];
#pragma unroll
        for (int j = 0; j < 4; ++j) {
            z1lds[lrow0 + j][col] = f2bf(fmaxf(acc0[ctl][j] + b, 0.f));
            z1lds[16 + lrow0 + j][col] = f2bf(fmaxf(acc1[ctl][j] + b, 0.f));
        }
    }
    __syncthreads();

    // ---- phase B: waves 0,1 -> 16 rows x 48 cols, K=128, + log-softmax
    if (wid < 2) {
        f32x4 acc[3];
#pragma unroll
        for (int t = 0; t < 3; ++t) acc[t] = (f32x4){0.f,0.f,0.f,0.f};
        int lr = wid * 16 + lrow;
#pragma unroll
        for (int kc = 0; kc < 4; ++kc) {
            short8 aF = *(const short8*)(&z1lds[lr][kc * 32 + lk8]);
#pragma unroll
            for (int ct = 0; ct < 3; ++ct) {
                short8 bF = *(const short8*)(W2T + (size_t)(ct * 16 + lrow) * 128 + kc * 32 + lk8);
                acc[ct] = __builtin_amdgcn_mfma_f32_16x16x32_bf16(aF, bF, acc[ct], 0, 0, 0);
            }
        }

        float b0 = b2[ocol];
        float b1v = b2[16 + ocol];
        float b2v = (ocol < 8) ? b2[32 + ocol] : 0.f;

#pragma unroll
        for (int j = 0; j < 4; ++j) {
            int orow = r0 + wid * 16 + (lane >> 4) * 4 + j;
            float v0 = acc[0][j] + b0;
            float v1 = acc[1][j] + b1v;
            float v2 = (ocol < 8) ? (acc[2][j] + b2v) : -1e30f;
            float mx = fmaxf(fmaxf(v0, v1), v2);
            mx = fmaxf(mx, __shfl_xor(mx, 1));
            mx = fmaxf(mx, __shfl_xor(mx, 2));
            mx = fmaxf(mx, __shfl_xor(mx, 4));
            mx = fmaxf(mx, __shfl_xor(mx, 8));
            float es = expf(v0 - mx) + expf(v1 - mx) + ((ocol < 8) ? expf(v2 - mx) : 0.f);
            es += __shfl_xor(es, 1);
            es += __shfl_xor(es, 2);
            es += __shfl_xor(es, 4);
            es += __shfl_xor(es, 8);
            float ls = logf(es);
            if (orow < N_NODES) {
                out[(size_t)orow * DOUT + ocol] = v0 - mx - ls;
                out[(size_t)orow * DOUT + 16 + ocol] = v1 - mx - ls;
                if (ocol < 8) out[(size_t)orow * DOUT + 32 + ocol] = v2 - mx - ls;
            }
        }
    }
}

// ---------------- launch ----------------

extern "C" void kernel_launch(void* const* d_in, const int* in_sizes, int n_in,
                              void* d_out, int out_size, void* d_ws, size_t ws_size,
                              hipStream_t stream) {
    const float* x   = (const float*)d_in[0];
    const int*   ei  = (const int*)d_in[1];
    const float* Wl  = (const float*)d_in[2];
    const float* Wr  = (const float*)d_in[3];
    const float* bl  = (const float*)d_in[4];
    const float* W1  = (const float*)d_in[5];
    const float* b1  = (const float*)d_in[6];
    const float* W2  = (const float*)d_in[7];
    const float* b2  = (const float*)d_in[8];
    float* out = (float*)d_out;

    const int E = in_sizes[1] / 2;
    const int* src = ei;
    const int* dst = ei + E;

    int CH = 2048;
    int nblk1 = (E + CH - 1) / CH;
    if (nblk1 > 512) { CH = ((E + 511) / 512 + 255) & ~255; nblk1 = (E + CH - 1) / CH; }

    char* p = (char*)d_ws;
    auto take = [&p](size_t bytes) { char* q = p; p += (bytes + 255) & ~(size_t)255; return q; };
    int* offs        = (int*)take((N_NODES + 1) * sizeof(int));
    int* H           = (int*)take((size_t)BUCKETS * nblk1 * sizeof(int));
    int* T           = (int*)take(BUCKETS * sizeof(int));
    int* bucketStart = (int*)take((BUCKETS + 1) * sizeof(int));
    unsigned int*   recs = (unsigned int*)take((size_t)E * sizeof(unsigned int));
    unsigned short* adj  = (unsigned short*)take((size_t)E * sizeof(unsigned short));
    unsigned short* xb  = (unsigned short*)take((size_t)N_NODES * D * 2);
    unsigned short* z0  = (unsigned short*)take((size_t)N_NODES * D * 2);
    unsigned short* z1  = (unsigned short*)take((size_t)N_NODES * D * 2);
    unsigned short* z2  = (unsigned short*)take((size_t)N_NODES * D * 2);
    unsigned short* WT  = (unsigned short*)take((size_t)LAYERS * 128 * 256 * 2);
    unsigned short* W1T = (unsigned short*)take((size_t)128 * 384 * 2);
    unsigned short* W2T = (unsigned short*)take((size_t)48 * 128 * 2);

    // prep: cvt + all weight packs in one kernel
    int n4 = N_NODES * D / 4;
    int prep_total = n4 + LAYERS * 128 * 256 + 128 * 384 + 48 * 128;
    prep_kernel<<<(prep_total + 255) / 256, 256, 0, stream>>>(
        x, Wl, Wr, W1, W2, xb, WT, W1T, W2T, n4);

    // CSR via counting sort (no global atomics)
    hist1_kernel<<<nblk1, 256, 0, stream>>>(dst, E, CH, nblk1, H);
    scanS_kernel<<<BUCKETS, 512, 0, stream>>>(H, nblk1, T);
    bstart_kernel<<<1, 256, 0, stream>>>(T, bucketStart, offs, E);
    scatter_kernel<<<nblk1, 256, 0, stream>>>(src, dst, E, CH, nblk1, H, bucketStart, recs);
    bucket_csr_kernel<<<BUCKETS, 256, 0, stream>>>(recs, bucketStart, offs, adj);

    int fgrid = (N_NODES + BR - 1) / BR;   // 1563

    unsigned short* zs[3] = {z0, z1, z2};
    for (int i = 0; i < LAYERS; ++i) {
        const unsigned short* hin = (i == 0) ? xb : zs[i - 1];
        sage_fused_kernel<<<fgrid, 256, 0, stream>>>(
            hin, offs, adj, WT + (size_t)i * 128 * 256, bl + (size_t)i * D, zs[i]);
    }

    mlp_fused_kernel<<<fgrid, 256, 0, stream>>>(z0, z1, z2, W1T, b1, W2T, b2, out);
}